// Round 3
// baseline (1896.602 us; speedup 1.0000x reference)
//
#include <hip/hip_runtime.h>

// ---------------------------------------------------------------------------
// AttentionStack: 6-layer transformer, B=2, SEQ=1024, E=576, H=16, DK=36.
// Inputs/outputs dtype auto-detected (f32 vs bf16) at runtime; internal
// pipeline: bf16 MFMA GEMMs + fp32 residual stream.
// ---------------------------------------------------------------------------

#define E_    576
#define SEQ_  1024
#define B_    2
#define NH_   16
#define DK_   36
#define DKP_  64          // DK padded to 64 for MFMA K-steps of 32
#define NL_   6
#define FF_   2304
#define ROWS_ 2048        // B_*SEQ_

typedef unsigned short u16;
typedef unsigned int u32;
typedef float f32x4 __attribute__((ext_vector_type(4)));
typedef __bf16 bf16x8 __attribute__((ext_vector_type(8)));

#define MFMA16(a, b, c) __builtin_amdgcn_mfma_f32_16x16x32_bf16((a), (b), (c), 0, 0, 0)

__device__ __forceinline__ float bf2f(u16 u) {
    return __uint_as_float(((unsigned)u) << 16);
}
__device__ __forceinline__ u16 f2bf(float f) {
    unsigned u = __float_as_uint(f);
    u += 0x7fffu + ((u >> 16) & 1u);   // round-to-nearest-even
    return (u16)(u >> 16);
}
// read input element i as float, per runtime dtype flag
__device__ __forceinline__ float load_in(const void* p, size_t i, int isf32) {
    return isf32 ? ((const float*)p)[i] : bf2f(((const u16*)p)[i]);
}
// read input element i as bf16 bits (no double-round when already bf16)
__device__ __forceinline__ u16 load_in_bf(const void* p, size_t i, int isf32) {
    return isf32 ? f2bf(((const float*)p)[i]) : ((const u16*)p)[i];
}
__device__ __forceinline__ bf16x8 ldg8(const u16* p) {
    uint4 u = *(const uint4*)p;        // 16B aligned by construction
    bf16x8 r;
    __builtin_memcpy(&r, &u, 16);
    return r;
}

// ---------------------------------------------------------------------------
// Dtype detect: if x's raw u16 stream, viewed as bf16, has huge magnitudes,
// the underlying data is f32 (low mantissa halves have random exponents).
// Genuine bf16 activations are O(10). One block of 256.
// ---------------------------------------------------------------------------
__global__ void detect_kernel(const u16* __restrict__ x, int* __restrict__ flag)
{
    __shared__ float red[4];
    int lane = threadIdx.x & 63, wave = threadIdx.x >> 6;
    float mx = 0.f;
    for (int i = threadIdx.x; i < 4096; i += 256) {
        float v = fabsf(bf2f(x[i]));
        if (v < 3e38f) mx = fmaxf(mx, v);   // skip NaN/Inf bit patterns
    }
    for (int off = 1; off < 64; off <<= 1) mx = fmaxf(mx, __shfl_xor(mx, off));
    if (lane == 0) red[wave] = mx;
    __syncthreads();
    if (threadIdx.x == 0) {
        float m = fmaxf(fmaxf(red[0], red[1]), fmaxf(red[2], red[3]));
        *flag = (m > 1e6f) ? 1 : 0;
    }
}

// ---------------------------------------------------------------------------
// Weight repack: W[K][N] -> W^T[N][K] bf16 so MFMA B-fragments are contiguous.
// grid (3888, 1, 6), block (32, 8). LDS-tiled 32x32 transpose.
// per-layer wT region: [wqT|wkT|wvT|woT][w1T (2304x576)][w2T (576x2304)]
// ---------------------------------------------------------------------------
__global__ __launch_bounds__(256) void repack_kernel(
    const void* __restrict__ wq, const void* __restrict__ wk,
    const void* __restrict__ wv, const void* __restrict__ wo,
    const void* __restrict__ w1, const void* __restrict__ w2,
    u16* __restrict__ wT, const int* __restrict__ flagp)
{
    __shared__ u16 tile[32][33];
    int isf32 = *flagp;
    int idx = blockIdx.x, l = blockIdx.z;
    const void* src;
    u16* dst;
    size_t sbase;
    int R, C, cx, ry;
    if (idx < 1296) {                       // wq/wk/wv/wo: 576x576, 324 tiles ea
        int t = idx / 324, rem = idx - t * 324;
        cx = rem % 18; ry = rem / 18; R = 576; C = 576;
        src = (t == 0) ? wq : (t == 1) ? wk : (t == 2) ? wv : wo;
        sbase = (size_t)l * 331776;
        dst = wT + (size_t)l * 3981312 + t * 331776;
    } else if (idx < 2592) {                // w1: 576x2304 -> 2304x576
        int rem = idx - 1296;
        cx = rem % 72; ry = rem / 72; R = 576; C = 2304;
        src = w1; sbase = (size_t)l * 1327104;
        dst = wT + (size_t)l * 3981312 + 1327104;
    } else {                                // w2: 2304x576 -> 576x2304
        int rem = idx - 2592;
        cx = rem % 18; ry = rem / 18; R = 2304; C = 576;
        src = w2; sbase = (size_t)l * 1327104;
        dst = wT + (size_t)l * 3981312 + 2654208;
    }
    int r0 = ry * 32, c0 = cx * 32;
    int tx = threadIdx.x, ty = threadIdx.y;
    for (int i = 0; i < 4; i++)
        tile[ty + i * 8][tx] =
            load_in_bf(src, sbase + (size_t)(r0 + ty + i * 8) * C + c0 + tx, isf32);
    __syncthreads();
    for (int i = 0; i < 4; i++)
        dst[(size_t)(c0 + ty + i * 8) * R + r0 + tx] = tile[tx][ty + i * 8];
}

// ---------------------------------------------------------------------------
// Embed: h = rightshift(x, sos) + concat(pe0[t], pe1[h], pe2[w]); fp32 out.
// grid ROWS_, block E_ (576 = 9 waves).
// ---------------------------------------------------------------------------
__global__ void embed_kernel(
    const void* __restrict__ x, const void* __restrict__ sos,
    const void* __restrict__ pe0, const void* __restrict__ pe1,
    const void* __restrict__ pe2, float* __restrict__ h,
    const int* __restrict__ flagp)
{
    int isf32 = *flagp;
    int row = blockIdx.x;        // b*1024 + s
    int e = threadIdx.x;
    int s = row & 1023;
    float v = (s == 0) ? load_in(sos, e, isf32)
                       : load_in(x, (size_t)(row - 1) * E_ + e, isf32);
    int t = s >> 8, hh = (s >> 4) & 15, ww = s & 15;
    float p = (e < 192) ? load_in(pe0, t * 192 + e, isf32)
            : (e < 384) ? load_in(pe1, hh * 192 + e - 192, isf32)
                        : load_in(pe2, ww * 192 + e - 384, isf32);
    h[(size_t)row * E_ + e] = v + p;
}

// ---------------------------------------------------------------------------
// LayerNorm: y(bf16) = (h - mean)/sqrt(var+1e-5)*s + b. One wave per row.
// grid 512, block 256.
// ---------------------------------------------------------------------------
__global__ __launch_bounds__(256) void ln_kernel(
    const float* __restrict__ h, u16* __restrict__ y,
    const void* __restrict__ sc, const void* __restrict__ bi,
    int off0, const int* __restrict__ flagp)
{
    int isf32 = *flagp;
    int lane = threadIdx.x & 63, wave = threadIdx.x >> 6;
    int row = blockIdx.x * 4 + wave;
    const float* hr = h + (size_t)row * E_;
    float v[9], s = 0.f, sq = 0.f;
    for (int j = 0; j < 9; j++) {
        v[j] = hr[lane + j * 64];
        s += v[j];
        sq += v[j] * v[j];
    }
    for (int off = 1; off < 64; off <<= 1) {
        s += __shfl_xor(s, off);
        sq += __shfl_xor(sq, off);
    }
    float mean = s * (1.0f / E_);
    float var = sq * (1.0f / E_) - mean * mean;
    float r = rsqrtf(var + 1e-5f);
    for (int j = 0; j < 9; j++) {
        int e = lane + j * 64;
        float sce = load_in(sc, off0 + e, isf32);
        float bie = load_in(bi, off0 + e, isf32);
        y[(size_t)row * E_ + e] = f2bf((v[j] - mean) * r * sce + bie);
    }
}

// ---------------------------------------------------------------------------
// GEMM: C[m,n] = sum_k A[m,k] * Bt[n,k].  Block = 64x64 tile, 4 waves; each
// wave: 64(M) x 16(N) via four 16x16x32 MFMAs sharing one B-fragment.
// MODE 0: QKV (z picks wq/wk/wv; writes q(scaled)/k/vt padded to DKP)
// MODE 1: O-proj: h += A@woT + bo
// MODE 2: MLP1:  y1 = gelu2(A@w1T + b1)        (N stride FF_)
// MODE 3: MLP2:  h += A@w2T + b2
// ---------------------------------------------------------------------------
template <int MODE>
__global__ __launch_bounds__(256) void gemm_kernel(
    const u16* __restrict__ A, const u16* __restrict__ BtBase, int K,
    const void* __restrict__ bias, int boff, float* __restrict__ hbuf,
    u16* __restrict__ out, u16* __restrict__ qb, u16* __restrict__ kb,
    u16* __restrict__ vtb, const int* __restrict__ flagp)
{
    int lane = threadIdx.x & 63, wave = threadIdx.x >> 6;
    int lw = lane & 15, lq = lane >> 4;
    int m0 = blockIdx.x * 64, n0 = blockIdx.y * 64;
    int z = blockIdx.z;
    const u16* Bt = BtBase + (MODE == 0 ? (size_t)z * 331776 : 0);
    const u16* brow = Bt + (size_t)(n0 + wave * 16 + lw) * K + lq * 8;
    const u16* arow = A + (size_t)(m0 + lw) * K + lq * 8;
    size_t astep = (size_t)16 * K;

    f32x4 acc[4];
    for (int mi = 0; mi < 4; mi++)
        for (int r = 0; r < 4; r++) acc[mi][r] = 0.f;

    for (int k0 = 0; k0 < K; k0 += 32) {
        bf16x8 bf = ldg8(brow + k0);
        #pragma unroll
        for (int mi = 0; mi < 4; mi++) {
            bf16x8 af = ldg8(arow + mi * astep + k0);
            acc[mi] = MFMA16(af, bf, acc[mi]);
        }
    }

    int isf32 = (MODE != 0) ? *flagp : 0;
    int n = n0 + wave * 16 + lw;
    float bn = (MODE != 0) ? load_in(bias, boff + n, isf32) : 0.f;
    #pragma unroll
    for (int mi = 0; mi < 4; mi++) {
        #pragma unroll
        for (int r = 0; r < 4; r++) {
            int m = m0 + mi * 16 + lq * 4 + r;
            float v = acc[mi][r];
            if (MODE == 0) {
                int b = m >> 10, s = m & 1023;
                int head = n / 36, d = n - head * 36;
                size_t bh = (size_t)(b * NH_ + head);
                if (z == 0)
                    qb[(bh * SEQ_ + s) * DKP_ + d] = f2bf(v * (1.0f / 6.0f));
                else if (z == 1)
                    kb[(bh * SEQ_ + s) * DKP_ + d] = f2bf(v);
                else
                    vtb[(bh * DKP_ + d) * SEQ_ + s] = f2bf(v);
            } else if (MODE == 1) {
                hbuf[(size_t)m * E_ + n] += v + bn;
            } else if (MODE == 2) {
                float t = v + bn;
                out[(size_t)m * FF_ + n] = f2bf(t / (1.0f + __expf(-1.702f * t)));
            } else {
                hbuf[(size_t)m * E_ + n] += v + bn;
            }
        }
    }
}

// ---------------------------------------------------------------------------
// Flash attention: one block per (64 q-rows, head, batch); 4 waves, each wave
// owns 16 q-rows. Online softmax; distance-decay mask computed on the fly.
// q/k: [b,h,seq,DKP_] bf16, vt: [b,h,DKP_,seq] bf16 (padding pre-zeroed).
// P round-trips LDS (C-layout -> A-layout), all accesses u32-typed.
// ---------------------------------------------------------------------------
__global__ __launch_bounds__(256) void attn_kernel(
    const u16* __restrict__ qb, const u16* __restrict__ kb,
    const u16* __restrict__ vtb, u16* __restrict__ ob)
{
    __shared__ u32 plds[4][16][17];
    int lane = threadIdx.x & 63, wave = threadIdx.x >> 6;
    int lw = lane & 15, lq = lane >> 4;
    int qt = blockIdx.x, head = blockIdx.y, b = blockIdx.z;
    int bh = b * NH_ + head;
    int q0 = qt * 64 + wave * 16;

    const u16* qbase = qb + ((size_t)bh * SEQ_ + q0) * DKP_;
    bf16x8 qf0 = ldg8(qbase + lw * DKP_ + lq * 8);
    bf16x8 qf1 = ldg8(qbase + lw * DKP_ + 32 + lq * 8);

    float m_i[4], l_i[4];
    f32x4 oacc[3];
    int qi[4], qc0[4], qc1[4], qc2[4];
    for (int r = 0; r < 4; r++) {
        m_i[r] = -1e30f;
        l_i[r] = 0.f;
        qi[r] = q0 + lq * 4 + r;
        qc0[r] = qi[r] >> 8; qc1[r] = (qi[r] >> 4) & 15; qc2[r] = qi[r] & 15;
    }
    for (int c = 0; c < 3; c++)
        for (int r = 0; r < 4; r++) oacc[c][r] = 0.f;

    int kv_end = q0 + 15;
    for (int kv0 = 0; kv0 <= kv_end; kv0 += 32) {
        f32x4 st[2];
        #pragma unroll
        for (int kvh = 0; kvh < 2; kvh++) {
            f32x4 t;
            for (int r = 0; r < 4; r++) t[r] = 0.f;
            const u16* krow =
                kb + ((size_t)bh * SEQ_ + kv0 + kvh * 16 + lw) * DKP_ + lq * 8;
            t = MFMA16(qf0, ldg8(krow), t);
            t = MFMA16(qf1, ldg8(krow + 32), t);
            st[kvh] = t;
        }
        #pragma unroll
        for (int r = 0; r < 4; r++) {
            #pragma unroll
            for (int kvh = 0; kvh < 2; kvh++) {
                int ki = kv0 + kvh * 16 + lw;
                int dist = abs((ki >> 8) - qc0[r]) + abs(((ki >> 4) & 15) - qc1[r])
                         + abs((ki & 15) - qc2[r]);
                float val = st[kvh][r] * __expf((float)dist * (-1.0f / 33.0f));
                if (ki > qi[r]) val = -1e30f;
                st[kvh][r] = val;
            }
            float m2 = fmaxf(st[0][r], st[1][r]);
            for (int off = 1; off < 16; off <<= 1)
                m2 = fmaxf(m2, __shfl_xor(m2, off));
            float mn = fmaxf(m_i[r], m2);
            float alpha = __expf(m_i[r] - mn);
            m_i[r] = mn;
            float p0 = __expf(st[0][r] - mn);
            float p1 = __expf(st[1][r] - mn);
            u32 both = (u32)f2bf(p0) | ((u32)f2bf(p1) << 16);
            u32 oboth = (u32)__shfl_xor((int)both, 1);
            if (!(lw & 1)) {
                int ro = lq * 4 + r;
                u32 pair0 = ((oboth & 0xffffu) << 16) | (both & 0xffffu);
                u32 pair1 = (oboth & 0xffff0000u) | (both >> 16);
                plds[wave][ro][lw >> 1] = pair0;       // keys kv0 + {lw, lw+1}
                plds[wave][ro][8 + (lw >> 1)] = pair1; // keys kv0+16 + {...}
            }
            float rs = p0 + p1;
            for (int off = 1; off < 16; off <<= 1)
                rs += __shfl_xor(rs, off);
            l_i[r] = l_i[r] * alpha + rs;
            for (int c = 0; c < 3; c++) oacc[c][r] *= alpha;
        }
        __asm__ volatile("s_waitcnt lgkmcnt(0)" ::: "memory");
        uint4 uu;
        uu.x = plds[wave][lw][lq * 4 + 0];
        uu.y = plds[wave][lw][lq * 4 + 1];
        uu.z = plds[wave][lw][lq * 4 + 2];
        uu.w = plds[wave][lw][lq * 4 + 3];
        bf16x8 pf;
        __builtin_memcpy(&pf, &uu, 16);
        #pragma unroll
        for (int c = 0; c < 3; c++) {   // d-chunks 0..47 (48..63 is padding)
            const u16* vrow =
                vtb + ((size_t)bh * DKP_ + c * 16 + lw) * SEQ_ + kv0 + lq * 8;
            oacc[c] = MFMA16(pf, ldg8(vrow), oacc[c]);
        }
    }
    #pragma unroll
    for (int c = 0; c < 3; c++) {
        int d = c * 16 + lw;
        if (d < DK_) {
            #pragma unroll
            for (int r = 0; r < 4; r++)
                ob[((size_t)b * SEQ_ + qi[r]) * E_ + head * DK_ + d] =
                    f2bf(oacc[c][r] / l_i[r]);
        }
    }
}

// ---------------------------------------------------------------------------
__global__ void out_kernel(const float* __restrict__ h, void* __restrict__ out,
                           const int* __restrict__ flagp)
{
    int isf32 = *flagp;
    int i = blockIdx.x * blockDim.x + threadIdx.x;
    if (isf32) ((float*)out)[i] = h[i];
    else       ((u16*)out)[i] = f2bf(h[i]);
}

// ---------------------------------------------------------------------------
extern "C" void kernel_launch(void* const* d_in, const int* in_sizes, int n_in,
                              void* d_out, int out_size, void* d_ws,
                              size_t ws_size, hipStream_t stream)
{
    const void* x    = d_in[0];
    const void* sos  = d_in[1];
    const void* pe0  = d_in[2];
    const void* pe1  = d_in[3];
    const void* pe2  = d_in[4];
    const void* ln1s = d_in[5];
    const void* ln1b = d_in[6];
    const void* wq   = d_in[7];
    const void* wk   = d_in[8];
    const void* wv   = d_in[9];
    const void* wo   = d_in[10];
    const void* bo   = d_in[11];
    const void* ln2s = d_in[12];
    const void* ln2b = d_in[13];
    const void* w1   = d_in[14];
    const void* b1   = d_in[15];
    const void* w2   = d_in[16];
    const void* b2   = d_in[17];

    char* ws = (char*)d_ws;
    u16*   qbuf  = (u16*)(ws + 0);          //  4 MB  [B,H,SEQ,64] bf16
    u16*   kbuf  = (u16*)(ws + 4194304);    //  4 MB
    u16*   vtbuf = (u16*)(ws + 8388608);    //  4 MB  [B,H,64,SEQ] bf16
    float* h     = (float*)(ws + 12582912); //  4.7 MB fp32 residual stream
    u16*   y     = (u16*)(ws + 17301504);   //  2.36 MB LN output
    u16*   o     = (u16*)(ws + 19660800);   //  2.36 MB attention output
    u16*   y1    = (u16*)(ws + 22020096);   //  9.4 MB MLP hidden
    u16*   wT    = (u16*)(ws + 31457280);   // 47.8 MB repacked weights
    int*   flag  = (int*)(ws + 79233024);   // dtype flag

    // zero q/k/vt so DK->DKP padding lanes stay 0 (ws is 0xAA-poisoned)
    hipMemsetAsync(ws, 0, 12582912, stream);
    detect_kernel<<<1, 256, 0, stream>>>((const u16*)x, flag);
    repack_kernel<<<dim3(3888, 1, 6), dim3(32, 8), 0, stream>>>(
        wq, wk, wv, wo, w1, w2, wT, flag);
    embed_kernel<<<ROWS_, E_, 0, stream>>>(x, sos, pe0, pe1, pe2, h, flag);

    for (int l = 0; l < NL_; l++) {
        u16* wTl = wT + (size_t)l * 3981312;
        ln_kernel<<<512, 256, 0, stream>>>(h, y, ln1s, ln1b, l * E_, flag);
        gemm_kernel<0><<<dim3(32, 9, 3), 256, 0, stream>>>(
            y, wTl, E_, nullptr, 0, nullptr, nullptr, qbuf, kbuf, vtbuf, flag);
        attn_kernel<<<dim3(16, NH_, B_), 256, 0, stream>>>(qbuf, kbuf, vtbuf, o);
        gemm_kernel<1><<<dim3(32, 9), 256, 0, stream>>>(
            o, wTl + 995328, E_, bo, l * E_, h, nullptr, nullptr, nullptr, nullptr, flag);
        ln_kernel<<<512, 256, 0, stream>>>(h, y, ln2s, ln2b, l * E_, flag);
        gemm_kernel<2><<<dim3(32, 36), 256, 0, stream>>>(
            y, wTl + 1327104, E_, b1, l * FF_, nullptr, y1, nullptr, nullptr, nullptr, flag);
        gemm_kernel<3><<<dim3(32, 9), 256, 0, stream>>>(
            y1, wTl + 2654208, FF_, b2, l * E_, h, nullptr, nullptr, nullptr, nullptr, flag);
    }
    out_kernel<<<4608, 256, 0, stream>>>(h, d_out, flag);
}

// Round 5
// 1010.453 us; speedup vs baseline: 1.8770x; 1.8770x over previous
//
#include <hip/hip_runtime.h>

// ---------------------------------------------------------------------------
// AttentionStack: 6-layer transformer, B=2, SEQ=1024, E=576, H=16, DK=36.
// Inputs/outputs dtype auto-detected (f32 vs bf16) at runtime; internal
// pipeline: bf16 MFMA GEMMs (LDS-staged, split-K) + fp32 residual stream.
// ---------------------------------------------------------------------------

#define E_    576
#define SEQ_  1024
#define B_    2
#define NH_   16
#define DK_   36
#define DKP_  64          // DK padded to 64 for MFMA K-steps of 32
#define NL_   6
#define FF_   2304
#define ROWS_ 2048        // B_*SEQ_

typedef unsigned short u16;
typedef unsigned int u32;
typedef float f32x4 __attribute__((ext_vector_type(4)));
typedef __bf16 bf16x8 __attribute__((ext_vector_type(8)));

#define MFMA16(a, b, c) __builtin_amdgcn_mfma_f32_16x16x32_bf16((a), (b), (c), 0, 0, 0)

__device__ __forceinline__ float bf2f(u16 u) {
    return __uint_as_float(((unsigned)u) << 16);
}
__device__ __forceinline__ u16 f2bf(float f) {
    unsigned u = __float_as_uint(f);
    u += 0x7fffu + ((u >> 16) & 1u);   // round-to-nearest-even
    return (u16)(u >> 16);
}
// read input element i as float, per runtime dtype flag
__device__ __forceinline__ float load_in(const void* p, size_t i, int isf32) {
    return isf32 ? ((const float*)p)[i] : bf2f(((const u16*)p)[i]);
}
// read input element i as bf16 bits (no double-round when already bf16)
__device__ __forceinline__ u16 load_in_bf(const void* p, size_t i, int isf32) {
    return isf32 ? f2bf(((const float*)p)[i]) : ((const u16*)p)[i];
}
__device__ __forceinline__ bf16x8 ldg8(const u16* p) {
    uint4 u = *(const uint4*)p;        // 16B aligned by construction
    bf16x8 r;
    __builtin_memcpy(&r, &u, 16);
    return r;
}
// async global->LDS, 16B per lane; LDS dest must be wave-uniform + lane*16
__device__ __forceinline__ void gload_lds16(const u16* g, u16* l) {
    __builtin_amdgcn_global_load_lds(
        (const __attribute__((address_space(1))) unsigned int*)g,
        (__attribute__((address_space(3))) unsigned int*)l, 16, 0, 0);
}

// ---------------------------------------------------------------------------
// Dtype detect: if x's raw u16 stream, viewed as bf16, has huge magnitudes,
// the underlying data is f32 (low mantissa halves have random exponents).
// ---------------------------------------------------------------------------
__global__ void detect_kernel(const u16* __restrict__ x, int* __restrict__ flag)
{
    __shared__ float red[4];
    int lane = threadIdx.x & 63, wave = threadIdx.x >> 6;
    float mx = 0.f;
    for (int i = threadIdx.x; i < 4096; i += 256) {
        float v = fabsf(bf2f(x[i]));
        if (v < 3e38f) mx = fmaxf(mx, v);   // skip NaN/Inf bit patterns
    }
    for (int off = 1; off < 64; off <<= 1) mx = fmaxf(mx, __shfl_xor(mx, off));
    if (lane == 0) red[wave] = mx;
    __syncthreads();
    if (threadIdx.x == 0) {
        float m = fmaxf(fmaxf(red[0], red[1]), fmaxf(red[2], red[3]));
        *flag = (m > 1e6f) ? 1 : 0;
    }
}

// ---------------------------------------------------------------------------
// Weight repack: W[K][N] -> W^T[N][K] bf16 so MFMA B-fragments are contiguous.
// grid (3888, 1, 6), block (32, 8). LDS-tiled 32x32 transpose.
// per-layer wT region: [wqT|wkT|wvT|woT][w1T (2304x576)][w2T (576x2304)]
// ---------------------------------------------------------------------------
__global__ __launch_bounds__(256) void repack_kernel(
    const void* __restrict__ wq, const void* __restrict__ wk,
    const void* __restrict__ wv, const void* __restrict__ wo,
    const void* __restrict__ w1, const void* __restrict__ w2,
    u16* __restrict__ wT, const int* __restrict__ flagp)
{
    __shared__ u16 tile[32][33];
    int isf32 = *flagp;
    int idx = blockIdx.x, l = blockIdx.z;
    const void* src;
    u16* dst;
    size_t sbase;
    int R, C, cx, ry;
    if (idx < 1296) {                       // wq/wk/wv/wo: 576x576, 324 tiles ea
        int t = idx / 324, rem = idx - t * 324;
        cx = rem % 18; ry = rem / 18; R = 576; C = 576;
        src = (t == 0) ? wq : (t == 1) ? wk : (t == 2) ? wv : wo;
        sbase = (size_t)l * 331776;
        dst = wT + (size_t)l * 3981312 + t * 331776;
    } else if (idx < 2592) {                // w1: 576x2304 -> 2304x576
        int rem = idx - 1296;
        cx = rem % 72; ry = rem / 72; R = 576; C = 2304;
        src = w1; sbase = (size_t)l * 1327104;
        dst = wT + (size_t)l * 3981312 + 1327104;
    } else {                                // w2: 2304x576 -> 576x2304
        int rem = idx - 2592;
        cx = rem % 18; ry = rem / 18; R = 2304; C = 576;
        src = w2; sbase = (size_t)l * 1327104;
        dst = wT + (size_t)l * 3981312 + 2654208;
    }
    int r0 = ry * 32, c0 = cx * 32;
    int tx = threadIdx.x, ty = threadIdx.y;
    for (int i = 0; i < 4; i++)
        tile[ty + i * 8][tx] =
            load_in_bf(src, sbase + (size_t)(r0 + ty + i * 8) * C + c0 + tx, isf32);
    __syncthreads();
    for (int i = 0; i < 4; i++)
        dst[(size_t)(c0 + ty + i * 8) * R + r0 + tx] = tile[tx][ty + i * 8];
}

// ---------------------------------------------------------------------------
// Embed: h = rightshift(x, sos) + concat(pe0[t], pe1[h], pe2[w]); fp32 out.
// ---------------------------------------------------------------------------
__global__ void embed_kernel(
    const void* __restrict__ x, const void* __restrict__ sos,
    const void* __restrict__ pe0, const void* __restrict__ pe1,
    const void* __restrict__ pe2, float* __restrict__ h,
    const int* __restrict__ flagp)
{
    int isf32 = *flagp;
    int row = blockIdx.x;        // b*1024 + s
    int e = threadIdx.x;
    int s = row & 1023;
    float v = (s == 0) ? load_in(sos, e, isf32)
                       : load_in(x, (size_t)(row - 1) * E_ + e, isf32);
    int t = s >> 8, hh = (s >> 4) & 15, ww = s & 15;
    float p = (e < 192) ? load_in(pe0, t * 192 + e, isf32)
            : (e < 384) ? load_in(pe1, hh * 192 + e - 192, isf32)
                        : load_in(pe2, ww * 192 + e - 384, isf32);
    h[(size_t)row * E_ + e] = v + p;
}

// ---------------------------------------------------------------------------
// LayerNorm: y(bf16) = (h - mean)/sqrt(var+1e-5)*s + b. One wave per row.
// ---------------------------------------------------------------------------
__global__ __launch_bounds__(256) void ln_kernel(
    const float* __restrict__ h, u16* __restrict__ y,
    const void* __restrict__ sc, const void* __restrict__ bi,
    int off0, const int* __restrict__ flagp)
{
    int isf32 = *flagp;
    int lane = threadIdx.x & 63, wave = threadIdx.x >> 6;
    int row = blockIdx.x * 4 + wave;
    const float* hr = h + (size_t)row * E_;
    float v[9], s = 0.f, sq = 0.f;
    for (int j = 0; j < 9; j++) {
        v[j] = hr[lane + j * 64];
        s += v[j];
        sq += v[j] * v[j];
    }
    for (int off = 1; off < 64; off <<= 1) {
        s += __shfl_xor(s, off);
        sq += __shfl_xor(sq, off);
    }
    float mean = s * (1.0f / E_);
    float var = sq * (1.0f / E_) - mean * mean;
    float r = rsqrtf(var + 1e-5f);
    for (int j = 0; j < 9; j++) {
        int e = lane + j * 64;
        float sce = load_in(sc, off0 + e, isf32);
        float bie = load_in(bi, off0 + e, isf32);
        y[(size_t)row * E_ + e] = f2bf((v[j] - mean) * r * sce + bie);
    }
}

// ---------------------------------------------------------------------------
// GEMM: C[m,n] = sum_k A[m,k] * Bt[n,k].  Block = 64x64 tile, 4 waves.
// LDS-staged (global_load_lds 16B, XOR chunk swizzle), BK=64, split-K.
// Each wave: 64(M) x 16(N) via four 16x16x32 MFMAs sharing one B-fragment.
// MODE 0: QKV (z picks wq/wk/wv; writes q(scaled)/k/vt padded to DKP)
// MODE 1: O-proj: h += A@woT + bo        (split-K 3, atomicAdd)
// MODE 2: MLP1:  y1 = gelu2(A@w1T + b1)  (N stride FF_)
// MODE 3: MLP2:  h += A@w2T + b2         (split-K 4, atomicAdd)
// ---------------------------------------------------------------------------
template <int MODE, int SPLITK>
__global__ __launch_bounds__(256) void gemm_kernel(
    const u16* __restrict__ A, const u16* __restrict__ BtBase, int K,
    const void* __restrict__ bias, int boff, float* __restrict__ hbuf,
    u16* __restrict__ out, u16* __restrict__ qb, u16* __restrict__ kb,
    u16* __restrict__ vtb, const int* __restrict__ flagp)
{
    __shared__ u16 lA[4096];     // 64 rows x 64 cols bf16 (8 KB)
    __shared__ u16 lB[4096];
    int t = threadIdx.x;
    int lane = t & 63, wave = t >> 6;
    int lw = lane & 15, lq = lane >> 4;
    int m0 = blockIdx.x * 64, n0 = blockIdx.y * 64;
    int z = blockIdx.z / SPLITK, kz = blockIdx.z % SPLITK;
    int Ks = K / SPLITK, kbase = kz * Ks;

    const u16* Bt = BtBase + (MODE == 0 ? (size_t)z * 331776 : 0);
    // staging: thread t covers LDS row t/8, chunk t%8 (16B); global chunk is
    // XOR-swizzled by row so ds_read_b128 fragments spread over all banks.
    int rowS = t >> 3;
    int gc = (t & 7) ^ (rowS & 7);
    const u16* gA = A + (size_t)(m0 + rowS) * K + kbase + gc * 8;
    const u16* gB = Bt + (size_t)(n0 + rowS) * K + kbase + gc * 8;
    u16* lA0 = &lA[t * 8];
    u16* lA1 = &lA[2048 + t * 8];
    u16* lB0 = &lB[t * 8];
    u16* lB1 = &lB[2048 + t * 8];
    size_t half = (size_t)32 * K;

    f32x4 acc[4];
    for (int mi = 0; mi < 4; mi++)
        for (int r = 0; r < 4; r++) acc[mi][r] = 0.f;

    for (int kc = 0; kc < Ks; kc += 64) {
        gload_lds16(gA + kc, lA0);
        gload_lds16(gA + kc + half, lA1);
        gload_lds16(gB + kc, lB0);
        gload_lds16(gB + kc + half, lB1);
        __syncthreads();
        #pragma unroll
        for (int ks = 0; ks < 2; ks++) {
            int csw = ((ks * 4 + lq) ^ (lw & 7)) * 8;
            bf16x8 bf = ldg8(&lB[(wave * 16 + lw) * 64 + csw]);
            #pragma unroll
            for (int mi = 0; mi < 4; mi++) {
                bf16x8 af = ldg8(&lA[(mi * 16 + lw) * 64 + csw]);
                acc[mi] = MFMA16(af, bf, acc[mi]);
            }
        }
        __syncthreads();
    }

    int isf32 = (MODE != 0) ? *flagp : 0;
    int n = n0 + wave * 16 + lw;
    float bn = 0.f;
    if (MODE == 2 || ((MODE == 1 || MODE == 3) && kz == 0))
        bn = load_in(bias, boff + n, isf32);
    #pragma unroll
    for (int mi = 0; mi < 4; mi++) {
        #pragma unroll
        for (int r = 0; r < 4; r++) {
            int m = m0 + mi * 16 + lq * 4 + r;
            float v = acc[mi][r];
            if (MODE == 0) {
                int b = m >> 10, s = m & 1023;
                int head = n / 36, d = n - head * 36;
                size_t bh = (size_t)(b * NH_ + head);
                if (z == 0)
                    qb[(bh * SEQ_ + s) * DKP_ + d] = f2bf(v * (1.0f / 6.0f));
                else if (z == 1)
                    kb[(bh * SEQ_ + s) * DKP_ + d] = f2bf(v);
                else
                    vtb[(bh * DKP_ + d) * SEQ_ + s] = f2bf(v);
            } else if (MODE == 2) {
                float tt = v + bn;
                out[(size_t)m * FF_ + n] = f2bf(tt / (1.0f + __expf(-1.702f * tt)));
            } else {
                atomicAdd(&hbuf[(size_t)m * E_ + n], v + bn);
            }
        }
    }
}

// ---------------------------------------------------------------------------
// Flash attention: one block per (64 q-rows, head, batch); 4 waves, each wave
// owns 16 q-rows. Online softmax; distance-decay mask computed on the fly.
// q/k: [b,h,seq,DKP_] bf16, vt: [b,h,DKP_,seq] bf16 (padding pre-zeroed).
// P round-trips LDS (C-layout -> A-layout), all accesses u32-typed.
// ---------------------------------------------------------------------------
__global__ __launch_bounds__(256) void attn_kernel(
    const u16* __restrict__ qb, const u16* __restrict__ kb,
    const u16* __restrict__ vtb, u16* __restrict__ ob)
{
    __shared__ u32 plds[4][16][17];
    int lane = threadIdx.x & 63, wave = threadIdx.x >> 6;
    int lw = lane & 15, lq = lane >> 4;
    int qt = blockIdx.x, head = blockIdx.y, b = blockIdx.z;
    int bh = b * NH_ + head;
    int q0 = qt * 64 + wave * 16;

    const u16* qbase = qb + ((size_t)bh * SEQ_ + q0) * DKP_;
    bf16x8 qf0 = ldg8(qbase + lw * DKP_ + lq * 8);
    bf16x8 qf1 = ldg8(qbase + lw * DKP_ + 32 + lq * 8);

    float m_i[4], l_i[4];
    f32x4 oacc[3];
    int qi[4], qc0[4], qc1[4], qc2[4];
    for (int r = 0; r < 4; r++) {
        m_i[r] = -1e30f;
        l_i[r] = 0.f;
        qi[r] = q0 + lq * 4 + r;
        qc0[r] = qi[r] >> 8; qc1[r] = (qi[r] >> 4) & 15; qc2[r] = qi[r] & 15;
    }
    for (int c = 0; c < 3; c++)
        for (int r = 0; r < 4; r++) oacc[c][r] = 0.f;

    int kv_end = q0 + 15;
    for (int kv0 = 0; kv0 <= kv_end; kv0 += 32) {
        f32x4 st[2];
        #pragma unroll
        for (int kvh = 0; kvh < 2; kvh++) {
            f32x4 t;
            for (int r = 0; r < 4; r++) t[r] = 0.f;
            const u16* krow =
                kb + ((size_t)bh * SEQ_ + kv0 + kvh * 16 + lw) * DKP_ + lq * 8;
            t = MFMA16(qf0, ldg8(krow), t);
            t = MFMA16(qf1, ldg8(krow + 32), t);
            st[kvh] = t;
        }
        #pragma unroll
        for (int r = 0; r < 4; r++) {
            #pragma unroll
            for (int kvh = 0; kvh < 2; kvh++) {
                int ki = kv0 + kvh * 16 + lw;
                int dist = abs((ki >> 8) - qc0[r]) + abs(((ki >> 4) & 15) - qc1[r])
                         + abs((ki & 15) - qc2[r]);
                float val = st[kvh][r] * __expf((float)dist * (-1.0f / 33.0f));
                if (ki > qi[r]) val = -1e30f;
                st[kvh][r] = val;
            }
            float m2 = fmaxf(st[0][r], st[1][r]);
            for (int off = 1; off < 16; off <<= 1)
                m2 = fmaxf(m2, __shfl_xor(m2, off));
            float mn = fmaxf(m_i[r], m2);
            float alpha = __expf(m_i[r] - mn);
            m_i[r] = mn;
            float p0 = __expf(st[0][r] - mn);
            float p1 = __expf(st[1][r] - mn);
            u32 both = (u32)f2bf(p0) | ((u32)f2bf(p1) << 16);
            u32 oboth = (u32)__shfl_xor((int)both, 1);
            if (!(lw & 1)) {
                int ro = lq * 4 + r;
                u32 pair0 = ((oboth & 0xffffu) << 16) | (both & 0xffffu);
                u32 pair1 = (oboth & 0xffff0000u) | (both >> 16);
                plds[wave][ro][lw >> 1] = pair0;       // keys kv0 + {lw, lw+1}
                plds[wave][ro][8 + (lw >> 1)] = pair1; // keys kv0+16 + {...}
            }
            float rs = p0 + p1;
            for (int off = 1; off < 16; off <<= 1)
                rs += __shfl_xor(rs, off);
            l_i[r] = l_i[r] * alpha + rs;
            for (int c = 0; c < 3; c++) oacc[c][r] *= alpha;
        }
        __asm__ volatile("s_waitcnt lgkmcnt(0)" ::: "memory");
        uint4 uu;
        uu.x = plds[wave][lw][lq * 4 + 0];
        uu.y = plds[wave][lw][lq * 4 + 1];
        uu.z = plds[wave][lw][lq * 4 + 2];
        uu.w = plds[wave][lw][lq * 4 + 3];
        bf16x8 pf;
        __builtin_memcpy(&pf, &uu, 16);
        #pragma unroll
        for (int c = 0; c < 3; c++) {   // d-chunks 0..47 (48..63 is padding)
            const u16* vrow =
                vtb + ((size_t)bh * DKP_ + c * 16 + lw) * SEQ_ + kv0 + lq * 8;
            oacc[c] = MFMA16(pf, ldg8(vrow), oacc[c]);
        }
    }
    #pragma unroll
    for (int c = 0; c < 3; c++) {
        int d = c * 16 + lw;
        if (d < DK_) {
            #pragma unroll
            for (int r = 0; r < 4; r++)
                ob[((size_t)b * SEQ_ + qi[r]) * E_ + head * DK_ + d] =
                    f2bf(oacc[c][r] / l_i[r]);
        }
    }
}

// ---------------------------------------------------------------------------
__global__ void out_kernel(const float* __restrict__ h, void* __restrict__ out,
                           const int* __restrict__ flagp)
{
    int isf32 = *flagp;
    int i = blockIdx.x * blockDim.x + threadIdx.x;
    if (isf32) ((float*)out)[i] = h[i];
    else       ((u16*)out)[i] = f2bf(h[i]);
}

// ---------------------------------------------------------------------------
extern "C" void kernel_launch(void* const* d_in, const int* in_sizes, int n_in,
                              void* d_out, int out_size, void* d_ws,
                              size_t ws_size, hipStream_t stream)
{
    const void* x    = d_in[0];
    const void* sos  = d_in[1];
    const void* pe0  = d_in[2];
    const void* pe1  = d_in[3];
    const void* pe2  = d_in[4];
    const void* ln1s = d_in[5];
    const void* ln1b = d_in[6];
    const void* wq   = d_in[7];
    const void* wk   = d_in[8];
    const void* wv   = d_in[9];
    const void* wo   = d_in[10];
    const void* bo   = d_in[11];
    const void* ln2s = d_in[12];
    const void* ln2b = d_in[13];
    const void* w1   = d_in[14];
    const void* b1   = d_in[15];
    const void* w2   = d_in[16];
    const void* b2   = d_in[17];

    char* ws = (char*)d_ws;
    u16*   qbuf  = (u16*)(ws + 0);          //  4 MB  [B,H,SEQ,64] bf16
    u16*   kbuf  = (u16*)(ws + 4194304);    //  4 MB
    u16*   vtbuf = (u16*)(ws + 8388608);    //  4 MB  [B,H,64,SEQ] bf16
    float* h     = (float*)(ws + 12582912); //  4.7 MB fp32 residual stream
    u16*   y     = (u16*)(ws + 17301504);   //  2.36 MB LN output
    u16*   o     = (u16*)(ws + 19660800);   //  2.36 MB attention output
    u16*   y1    = (u16*)(ws + 22020096);   //  9.4 MB MLP hidden
    u16*   wT    = (u16*)(ws + 31457280);   // 47.8 MB repacked weights
    int*   flag  = (int*)(ws + 79233024);   // dtype flag

    // zero q/k/vt so DK->DKP padding lanes stay 0 (ws is 0xAA-poisoned)
    hipMemsetAsync(ws, 0, 12582912, stream);
    detect_kernel<<<1, 256, 0, stream>>>((const u16*)x, flag);
    repack_kernel<<<dim3(3888, 1, 6), dim3(32, 8), 0, stream>>>(
        wq, wk, wv, wo, w1, w2, wT, flag);
    embed_kernel<<<ROWS_, E_, 0, stream>>>(x, sos, pe0, pe1, pe2, h, flag);

    for (int l = 0; l < NL_; l++) {
        u16* wTl = wT + (size_t)l * 3981312;
        ln_kernel<<<512, 256, 0, stream>>>(h, y, ln1s, ln1b, l * E_, flag);
        gemm_kernel<0, 1><<<dim3(32, 9, 3), 256, 0, stream>>>(
            y, wTl, E_, nullptr, 0, nullptr, nullptr, qbuf, kbuf, vtbuf, flag);
        attn_kernel<<<dim3(16, NH_, B_), 256, 0, stream>>>(qbuf, kbuf, vtbuf, o);
        gemm_kernel<1, 3><<<dim3(32, 9, 3), 256, 0, stream>>>(
            o, wTl + 995328, E_, bo, l * E_, h, nullptr, nullptr, nullptr, nullptr, flag);
        ln_kernel<<<512, 256, 0, stream>>>(h, y, ln2s, ln2b, l * E_, flag);
        gemm_kernel<2, 1><<<dim3(32, 36, 1), 256, 0, stream>>>(
            y, wTl + 1327104, E_, b1, l * FF_, nullptr, y1, nullptr, nullptr, nullptr, flag);
        gemm_kernel<3, 4><<<dim3(32, 9, 4), 256, 0, stream>>>(
            y1, wTl + 2654208, FF_, b2, l * E_, h, nullptr, nullptr, nullptr, nullptr, flag);
    }
    out_kernel<<<4608, 256, 0, stream>>>(h, d_out, flag);
}

// Round 6
// 949.906 us; speedup vs baseline: 1.9966x; 1.0637x over previous
//
#include <hip/hip_runtime.h>

// ---------------------------------------------------------------------------
// AttentionStack: 6-layer transformer, B=2, SEQ=1024, E=576, H=16, DK=36.
// Inputs/outputs dtype auto-detected (f32 vs bf16) at runtime; internal
// pipeline: bf16 MFMA GEMMs (LDS-staged, split-K) + fp32 residual stream.
// ---------------------------------------------------------------------------

#define E_    576
#define SEQ_  1024
#define B_    2
#define NH_   16
#define DK_   36
#define DKP_  64          // DK padded to 64 for MFMA K-steps of 32
#define NL_   6
#define FF_   2304
#define ROWS_ 2048        // B_*SEQ_

typedef unsigned short u16;
typedef unsigned int u32;
typedef float f32x4 __attribute__((ext_vector_type(4)));
typedef __bf16 bf16x8 __attribute__((ext_vector_type(8)));

#define MFMA16(a, b, c) __builtin_amdgcn_mfma_f32_16x16x32_bf16((a), (b), (c), 0, 0, 0)

__device__ __forceinline__ float bf2f(u16 u) {
    return __uint_as_float(((unsigned)u) << 16);
}
__device__ __forceinline__ u16 f2bf(float f) {
    unsigned u = __float_as_uint(f);
    u += 0x7fffu + ((u >> 16) & 1u);   // round-to-nearest-even
    return (u16)(u >> 16);
}
// read input element i as float, per runtime dtype flag
__device__ __forceinline__ float load_in(const void* p, size_t i, int isf32) {
    return isf32 ? ((const float*)p)[i] : bf2f(((const u16*)p)[i]);
}
// read input element i as bf16 bits (no double-round when already bf16)
__device__ __forceinline__ u16 load_in_bf(const void* p, size_t i, int isf32) {
    return isf32 ? f2bf(((const float*)p)[i]) : ((const u16*)p)[i];
}
__device__ __forceinline__ bf16x8 ldg8(const u16* p) {
    uint4 u = *(const uint4*)p;        // 16B aligned by construction
    bf16x8 r;
    __builtin_memcpy(&r, &u, 16);
    return r;
}
// async global->LDS, 16B per lane; LDS dest must be wave-uniform + lane*16
__device__ __forceinline__ void gload_lds16(const u16* g, u16* l) {
    __builtin_amdgcn_global_load_lds(
        (const __attribute__((address_space(1))) unsigned int*)g,
        (__attribute__((address_space(3))) unsigned int*)l, 16, 0, 0);
}

// ---------------------------------------------------------------------------
// Dtype detect: if x's raw u16 stream, viewed as bf16, has huge magnitudes,
// the underlying data is f32 (low mantissa halves have random exponents).
// ---------------------------------------------------------------------------
__global__ void detect_kernel(const u16* __restrict__ x, int* __restrict__ flag)
{
    __shared__ float red[4];
    int lane = threadIdx.x & 63, wave = threadIdx.x >> 6;
    float mx = 0.f;
    for (int i = threadIdx.x; i < 4096; i += 256) {
        float v = fabsf(bf2f(x[i]));
        if (v < 3e38f) mx = fmaxf(mx, v);   // skip NaN/Inf bit patterns
    }
    for (int off = 1; off < 64; off <<= 1) mx = fmaxf(mx, __shfl_xor(mx, off));
    if (lane == 0) red[wave] = mx;
    __syncthreads();
    if (threadIdx.x == 0) {
        float m = fmaxf(fmaxf(red[0], red[1]), fmaxf(red[2], red[3]));
        *flag = (m > 1e6f) ? 1 : 0;
    }
}

// ---------------------------------------------------------------------------
// Weight repack: W[K][N] -> W^T[N][K] bf16 so MFMA B-fragments are contiguous.
// grid (3888, 1, 6), block (32, 8). LDS-tiled 32x32 transpose.
// per-layer wT region: [wqT|wkT|wvT|woT][w1T (2304x576)][w2T (576x2304)]
// ---------------------------------------------------------------------------
__global__ __launch_bounds__(256) void repack_kernel(
    const void* __restrict__ wq, const void* __restrict__ wk,
    const void* __restrict__ wv, const void* __restrict__ wo,
    const void* __restrict__ w1, const void* __restrict__ w2,
    u16* __restrict__ wT, const int* __restrict__ flagp)
{
    __shared__ u16 tile[32][33];
    int isf32 = *flagp;
    int idx = blockIdx.x, l = blockIdx.z;
    const void* src;
    u16* dst;
    size_t sbase;
    int R, C, cx, ry;
    if (idx < 1296) {                       // wq/wk/wv/wo: 576x576, 324 tiles ea
        int t = idx / 324, rem = idx - t * 324;
        cx = rem % 18; ry = rem / 18; R = 576; C = 576;
        src = (t == 0) ? wq : (t == 1) ? wk : (t == 2) ? wv : wo;
        sbase = (size_t)l * 331776;
        dst = wT + (size_t)l * 3981312 + t * 331776;
    } else if (idx < 2592) {                // w1: 576x2304 -> 2304x576
        int rem = idx - 1296;
        cx = rem % 72; ry = rem / 72; R = 576; C = 2304;
        src = w1; sbase = (size_t)l * 1327104;
        dst = wT + (size_t)l * 3981312 + 1327104;
    } else {                                // w2: 2304x576 -> 576x2304
        int rem = idx - 2592;
        cx = rem % 18; ry = rem / 18; R = 2304; C = 576;
        src = w2; sbase = (size_t)l * 1327104;
        dst = wT + (size_t)l * 3981312 + 2654208;
    }
    int r0 = ry * 32, c0 = cx * 32;
    int tx = threadIdx.x, ty = threadIdx.y;
    for (int i = 0; i < 4; i++)
        tile[ty + i * 8][tx] =
            load_in_bf(src, sbase + (size_t)(r0 + ty + i * 8) * C + c0 + tx, isf32);
    __syncthreads();
    for (int i = 0; i < 4; i++)
        dst[(size_t)(c0 + ty + i * 8) * R + r0 + tx] = tile[tx][ty + i * 8];
}

// ---------------------------------------------------------------------------
// Embed: h = rightshift(x, sos) + concat(pe0[t], pe1[h], pe2[w]); fp32 out.
// ---------------------------------------------------------------------------
__global__ void embed_kernel(
    const void* __restrict__ x, const void* __restrict__ sos,
    const void* __restrict__ pe0, const void* __restrict__ pe1,
    const void* __restrict__ pe2, float* __restrict__ h,
    const int* __restrict__ flagp)
{
    int isf32 = *flagp;
    int row = blockIdx.x;        // b*1024 + s
    int e = threadIdx.x;
    int s = row & 1023;
    float v = (s == 0) ? load_in(sos, e, isf32)
                       : load_in(x, (size_t)(row - 1) * E_ + e, isf32);
    int t = s >> 8, hh = (s >> 4) & 15, ww = s & 15;
    float p = (e < 192) ? load_in(pe0, t * 192 + e, isf32)
            : (e < 384) ? load_in(pe1, hh * 192 + e - 192, isf32)
                        : load_in(pe2, ww * 192 + e - 384, isf32);
    h[(size_t)row * E_ + e] = v + p;
}

// ---------------------------------------------------------------------------
// LayerNorm: y(bf16) = (h - mean)/sqrt(var+1e-5)*s + b. One wave per row.
// ---------------------------------------------------------------------------
__global__ __launch_bounds__(256) void ln_kernel(
    const float* __restrict__ h, u16* __restrict__ y,
    const void* __restrict__ sc, const void* __restrict__ bi,
    int off0, const int* __restrict__ flagp)
{
    int isf32 = *flagp;
    int lane = threadIdx.x & 63, wave = threadIdx.x >> 6;
    int row = blockIdx.x * 4 + wave;
    const float* hr = h + (size_t)row * E_;
    float v[9], s = 0.f, sq = 0.f;
    for (int j = 0; j < 9; j++) {
        v[j] = hr[lane + j * 64];
        s += v[j];
        sq += v[j] * v[j];
    }
    for (int off = 1; off < 64; off <<= 1) {
        s += __shfl_xor(s, off);
        sq += __shfl_xor(sq, off);
    }
    float mean = s * (1.0f / E_);
    float var = sq * (1.0f / E_) - mean * mean;
    float r = rsqrtf(var + 1e-5f);
    for (int j = 0; j < 9; j++) {
        int e = lane + j * 64;
        float sce = load_in(sc, off0 + e, isf32);
        float bie = load_in(bi, off0 + e, isf32);
        y[(size_t)row * E_ + e] = f2bf((v[j] - mean) * r * sce + bie);
    }
}

// ---------------------------------------------------------------------------
// GEMM: C[m,n] = sum_k A[m,k] * Bt[n,k].  Block = 64x64 tile, 4 waves.
// LDS-staged (global_load_lds 16B, XOR chunk swizzle), BK=64, split-K.
// MODE 0: QKV (z picks wq/wk/wv; writes q(scaled)/k/vt padded to DKP)
// MODE 1: O-proj: h += A@woT + bo        (split-K 3, atomicAdd)
// MODE 2: MLP1:  y1 = gelu2(A@w1T + b1)  (N stride FF_)
// MODE 3: MLP2:  h += A@w2T + b2         (split-K 4, atomicAdd)
// ---------------------------------------------------------------------------
template <int MODE, int SPLITK>
__global__ __launch_bounds__(256) void gemm_kernel(
    const u16* __restrict__ A, const u16* __restrict__ BtBase, int K,
    const void* __restrict__ bias, int boff, float* __restrict__ hbuf,
    u16* __restrict__ out, u16* __restrict__ qb, u16* __restrict__ kb,
    u16* __restrict__ vtb, const int* __restrict__ flagp)
{
    __shared__ u16 lA[4096];     // 64 rows x 64 cols bf16 (8 KB)
    __shared__ u16 lB[4096];
    int t = threadIdx.x;
    int lane = t & 63, wave = t >> 6;
    int lw = lane & 15, lq = lane >> 4;
    int m0 = blockIdx.x * 64, n0 = blockIdx.y * 64;
    int z = blockIdx.z / SPLITK, kz = blockIdx.z % SPLITK;
    int Ks = K / SPLITK, kbase = kz * Ks;

    const u16* Bt = BtBase + (MODE == 0 ? (size_t)z * 331776 : 0);
    // staging: thread t covers LDS row t/8, chunk t%8 (16B); global chunk is
    // XOR-swizzled by row so ds_read_b128 fragments spread over all banks.
    int rowS = t >> 3;
    int gc = (t & 7) ^ (rowS & 7);
    const u16* gA = A + (size_t)(m0 + rowS) * K + kbase + gc * 8;
    const u16* gB = Bt + (size_t)(n0 + rowS) * K + kbase + gc * 8;
    u16* lA0 = &lA[t * 8];
    u16* lA1 = &lA[2048 + t * 8];
    u16* lB0 = &lB[t * 8];
    u16* lB1 = &lB[2048 + t * 8];
    size_t half = (size_t)32 * K;

    f32x4 acc[4];
    for (int mi = 0; mi < 4; mi++)
        for (int r = 0; r < 4; r++) acc[mi][r] = 0.f;

    for (int kc = 0; kc < Ks; kc += 64) {
        gload_lds16(gA + kc, lA0);
        gload_lds16(gA + kc + half, lA1);
        gload_lds16(gB + kc, lB0);
        gload_lds16(gB + kc + half, lB1);
        __syncthreads();
        #pragma unroll
        for (int ks = 0; ks < 2; ks++) {
            int csw = ((ks * 4 + lq) ^ (lw & 7)) * 8;
            bf16x8 bf = ldg8(&lB[(wave * 16 + lw) * 64 + csw]);
            #pragma unroll
            for (int mi = 0; mi < 4; mi++) {
                bf16x8 af = ldg8(&lA[(mi * 16 + lw) * 64 + csw]);
                acc[mi] = MFMA16(af, bf, acc[mi]);
            }
        }
        __syncthreads();
    }

    int isf32 = (MODE != 0) ? *flagp : 0;
    int n = n0 + wave * 16 + lw;
    float bn = 0.f;
    if (MODE == 2 || ((MODE == 1 || MODE == 3) && kz == 0))
        bn = load_in(bias, boff + n, isf32);
    #pragma unroll
    for (int mi = 0; mi < 4; mi++) {
        #pragma unroll
        for (int r = 0; r < 4; r++) {
            int m = m0 + mi * 16 + lq * 4 + r;
            float v = acc[mi][r];
            if (MODE == 0) {
                int b = m >> 10, s = m & 1023;
                int head = n / 36, d = n - head * 36;
                size_t bh = (size_t)(b * NH_ + head);
                if (z == 0)
                    qb[(bh * SEQ_ + s) * DKP_ + d] = f2bf(v * (1.0f / 6.0f));
                else if (z == 1)
                    kb[(bh * SEQ_ + s) * DKP_ + d] = f2bf(v);
                else
                    vtb[(bh * DKP_ + d) * SEQ_ + s] = f2bf(v);
            } else if (MODE == 2) {
                float tt = v + bn;
                out[(size_t)m * FF_ + n] = f2bf(tt / (1.0f + __expf(-1.702f * tt)));
            } else {
                atomicAdd(&hbuf[(size_t)m * E_ + n], v + bn);
            }
        }
    }
}

// ---------------------------------------------------------------------------
// Flash attention v2: block = 16 q-rows x (head, batch); 4 waves SPLIT THE KV
// RANGE (chunks of 64 keys round-robin) and merge partial (m,l,O) via LDS.
// dm mask decomposition: with q0 16-aligned and kv0 64-aligned,
//   t_q,h_q wave-uniform; t_k,h_k uniform per kvh; w_q=lq*4+r, w_k=lw.
//   dm = exp(-(|dt|+|dh|)/33) * exp(-|lw-w_q|/33) = sA[kvh] * ew[r]
// -> 4 scalar exps per chunk + 4 per-kernel exps; 1 mul per score.
// Causal masking only in the (single) diagonal chunk per q-tile.
// ---------------------------------------------------------------------------
__global__ __launch_bounds__(256) void attn_kernel(
    const u16* __restrict__ qb, const u16* __restrict__ kb,
    const u16* __restrict__ vtb, u16* __restrict__ ob)
{
    __shared__ u32 plds[4][16][33];       // per-wave P: 16 rows x 64 keys bf16
    __shared__ float sm[4][16], sl[4][16];
    __shared__ float so[4][16][52];       // 48 used, padded
    int lane = threadIdx.x & 63, wave = threadIdx.x >> 6;
    int lw = lane & 15, lq = lane >> 4;
    int qt = 63 - blockIdx.x;             // longest kv ranges launch first
    int head = blockIdx.y, b = blockIdx.z;
    int bh = b * NH_ + head;
    int q0 = qt * 16;

    const u16* qbase = qb + ((size_t)bh * SEQ_ + q0) * DKP_;
    bf16x8 qf0 = ldg8(qbase + lw * DKP_ + lq * 8);
    bf16x8 qf1 = ldg8(qbase + lw * DKP_ + 32 + lq * 8);

    int tq = q0 >> 8, hq = (q0 >> 4) & 15;
    float m_i[4], l_i[4], ew[4];
    f32x4 oacc[3];
    int qi[4];
    for (int r = 0; r < 4; r++) {
        m_i[r] = -1e30f;
        l_i[r] = 0.f;
        qi[r] = q0 + lq * 4 + r;
        ew[r] = __expf((float)abs(lw - (lq * 4 + r)) * (-1.0f / 33.0f));
    }
    for (int c = 0; c < 3; c++)
        for (int r = 0; r < 4; r++) oacc[c][r] = 0.f;

    int nch = (q0 + 79) >> 6;             // ceil((q0+16)/64)
    for (int c = wave; c < nch; c += 4) {
        int kv0 = c * 64;
        bool diag = (c == nch - 1);
        // --- load all K/V fragments for this chunk (independent 16B loads) ---
        bf16x8 kf[4][2], vf[3][2];
        #pragma unroll
        for (int kvh = 0; kvh < 4; kvh++) {
            const u16* krow =
                kb + ((size_t)bh * SEQ_ + kv0 + kvh * 16 + lw) * DKP_ + lq * 8;
            kf[kvh][0] = ldg8(krow);
            kf[kvh][1] = ldg8(krow + 32);
        }
        #pragma unroll
        for (int c2 = 0; c2 < 3; c2++) {
            const u16* vrow =
                vtb + ((size_t)bh * DKP_ + c2 * 16 + lw) * SEQ_ + kv0 + lq * 8;
            vf[c2][0] = ldg8(vrow);
            vf[c2][1] = ldg8(vrow + 32);
        }
        // --- S = (Q*scale) K^T : four 16x16 tiles ---
        f32x4 st[4];
        #pragma unroll
        for (int kvh = 0; kvh < 4; kvh++) {
            f32x4 t;
            for (int r = 0; r < 4; r++) t[r] = 0.f;
            t = MFMA16(qf0, kf[kvh][0], t);
            t = MFMA16(qf1, kf[kvh][1], t);
            st[kvh] = t;
        }
        // --- uniform part of dm ---
        float sA[4];
        #pragma unroll
        for (int kvh = 0; kvh < 4; kvh++) {
            int kk = kv0 + kvh * 16;
            int d = abs((kk >> 8) - tq) + abs(((kk >> 4) & 15) - hq);
            sA[kvh] = __expf((float)d * (-1.0f / 33.0f));
        }
        // --- online softmax per q-row ---
        #pragma unroll
        for (int r = 0; r < 4; r++) {
            float v0 = st[0][r] * (sA[0] * ew[r]);
            float v1 = st[1][r] * (sA[1] * ew[r]);
            float v2 = st[2][r] * (sA[2] * ew[r]);
            float v3 = st[3][r] * (sA[3] * ew[r]);
            if (diag) {
                if (kv0 + 0 * 16 + lw > qi[r]) v0 = -1e30f;
                if (kv0 + 1 * 16 + lw > qi[r]) v1 = -1e30f;
                if (kv0 + 2 * 16 + lw > qi[r]) v2 = -1e30f;
                if (kv0 + 3 * 16 + lw > qi[r]) v3 = -1e30f;
            }
            float m2 = fmaxf(fmaxf(v0, v1), fmaxf(v2, v3));
            for (int off = 1; off < 16; off <<= 1)
                m2 = fmaxf(m2, __shfl_xor(m2, off));
            float mn = fmaxf(m_i[r], m2);
            float alpha = __expf(m_i[r] - mn);
            m_i[r] = mn;
            float p0 = __expf(v0 - mn), p1 = __expf(v1 - mn);
            float p2 = __expf(v2 - mn), p3 = __expf(v3 - mn);
            // pack adjacent keys (lanes lw, lw^1) into u32 pairs
            u32 a01 = (u32)f2bf(p0) | ((u32)f2bf(p1) << 16);
            u32 a23 = (u32)f2bf(p2) | ((u32)f2bf(p3) << 16);
            u32 b01 = (u32)__shfl_xor((int)a01, 1);
            u32 b23 = (u32)__shfl_xor((int)a23, 1);
            if (!(lw & 1)) {
                int ro = lq * 4 + r, w2 = lw >> 1;
                plds[wave][ro][w2 + 0]  = ((b01 & 0xffffu) << 16) | (a01 & 0xffffu);
                plds[wave][ro][w2 + 8]  = (b01 & 0xffff0000u) | (a01 >> 16);
                plds[wave][ro][w2 + 16] = ((b23 & 0xffffu) << 16) | (a23 & 0xffffu);
                plds[wave][ro][w2 + 24] = (b23 & 0xffff0000u) | (a23 >> 16);
            }
            float rs = (p0 + p1) + (p2 + p3);
            for (int off = 1; off < 16; off <<= 1)
                rs += __shfl_xor(rs, off);
            l_i[r] = l_i[r] * alpha + rs;
            for (int c2 = 0; c2 < 3; c2++) oacc[c2][r] *= alpha;
        }
        __asm__ volatile("s_waitcnt lgkmcnt(0)" ::: "memory");
        // --- O += P V ---
        uint4 u0 = *(const uint4*)&plds[wave][lw][lq * 4];
        uint4 u1 = *(const uint4*)&plds[wave][lw][16 + lq * 4];
        bf16x8 pf0, pf1;
        __builtin_memcpy(&pf0, &u0, 16);
        __builtin_memcpy(&pf1, &u1, 16);
        #pragma unroll
        for (int c2 = 0; c2 < 3; c2++) {
            oacc[c2] = MFMA16(pf0, vf[c2][0], oacc[c2]);
            oacc[c2] = MFMA16(pf1, vf[c2][1], oacc[c2]);
        }
    }
    // --- publish per-wave state, merge flash-decode style ---
    #pragma unroll
    for (int r = 0; r < 4; r++) {
        int ro = lq * 4 + r;
        if (lw == 0) { sm[wave][ro] = m_i[r]; sl[wave][ro] = l_i[r]; }
        for (int c2 = 0; c2 < 3; c2++)
            so[wave][ro][c2 * 16 + lw] = oacc[c2][r];
    }
    __syncthreads();
    for (int i = threadIdx.x; i < 16 * DK_; i += 256) {
        int row = i / DK_, col = i - row * DK_;
        float M = fmaxf(fmaxf(sm[0][row], sm[1][row]),
                        fmaxf(sm[2][row], sm[3][row]));
        float L = 0.f, O = 0.f;
        #pragma unroll
        for (int w = 0; w < 4; w++) {
            float f = __expf(sm[w][row] - M);
            L += f * sl[w][row];
            O += f * so[w][row][col];
        }
        ob[((size_t)b * SEQ_ + q0 + row) * E_ + head * DK_ + col] = f2bf(O / L);
    }
}

// ---------------------------------------------------------------------------
__global__ void out_kernel(const float* __restrict__ h, void* __restrict__ out,
                           const int* __restrict__ flagp)
{
    int isf32 = *flagp;
    int i = blockIdx.x * blockDim.x + threadIdx.x;
    if (isf32) ((float*)out)[i] = h[i];
    else       ((u16*)out)[i] = f2bf(h[i]);
}

// ---------------------------------------------------------------------------
extern "C" void kernel_launch(void* const* d_in, const int* in_sizes, int n_in,
                              void* d_out, int out_size, void* d_ws,
                              size_t ws_size, hipStream_t stream)
{
    const void* x    = d_in[0];
    const void* sos  = d_in[1];
    const void* pe0  = d_in[2];
    const void* pe1  = d_in[3];
    const void* pe2  = d_in[4];
    const void* ln1s = d_in[5];
    const void* ln1b = d_in[6];
    const void* wq   = d_in[7];
    const void* wk   = d_in[8];
    const void* wv   = d_in[9];
    const void* wo   = d_in[10];
    const void* bo   = d_in[11];
    const void* ln2s = d_in[12];
    const void* ln2b = d_in[13];
    const void* w1   = d_in[14];
    const void* b1   = d_in[15];
    const void* w2   = d_in[16];
    const void* b2   = d_in[17];

    char* ws = (char*)d_ws;
    u16*   qbuf  = (u16*)(ws + 0);          //  4 MB  [B,H,SEQ,64] bf16
    u16*   kbuf  = (u16*)(ws + 4194304);    //  4 MB
    u16*   vtbuf = (u16*)(ws + 8388608);    //  4 MB  [B,H,64,SEQ] bf16
    float* h     = (float*)(ws + 12582912); //  4.7 MB fp32 residual stream
    u16*   y     = (u16*)(ws + 17301504);   //  2.36 MB LN output
    u16*   o     = (u16*)(ws + 19660800);   //  2.36 MB attention output
    u16*   y1    = (u16*)(ws + 22020096);   //  9.4 MB MLP hidden
    u16*   wT    = (u16*)(ws + 31457280);   // 47.8 MB repacked weights
    int*   flag  = (int*)(ws + 79233024);   // dtype flag

    // zero q/k/vt so DK->DKP padding lanes stay 0 (ws is 0xAA-poisoned)
    hipMemsetAsync(ws, 0, 12582912, stream);
    detect_kernel<<<1, 256, 0, stream>>>((const u16*)x, flag);
    repack_kernel<<<dim3(3888, 1, 6), dim3(32, 8), 0, stream>>>(
        wq, wk, wv, wo, w1, w2, wT, flag);
    embed_kernel<<<ROWS_, E_, 0, stream>>>(x, sos, pe0, pe1, pe2, h, flag);

    for (int l = 0; l < NL_; l++) {
        u16* wTl = wT + (size_t)l * 3981312;
        ln_kernel<<<512, 256, 0, stream>>>(h, y, ln1s, ln1b, l * E_, flag);
        gemm_kernel<0, 1><<<dim3(32, 9, 3), 256, 0, stream>>>(
            y, wTl, E_, nullptr, 0, nullptr, nullptr, qbuf, kbuf, vtbuf, flag);
        attn_kernel<<<dim3(64, NH_, B_), 256, 0, stream>>>(qbuf, kbuf, vtbuf, o);
        gemm_kernel<1, 3><<<dim3(32, 9, 3), 256, 0, stream>>>(
            o, wTl + 995328, E_, bo, l * E_, h, nullptr, nullptr, nullptr, nullptr, flag);
        ln_kernel<<<512, 256, 0, stream>>>(h, y, ln2s, ln2b, l * E_, flag);
        gemm_kernel<2, 1><<<dim3(32, 36, 1), 256, 0, stream>>>(
            y, wTl + 1327104, E_, b1, l * FF_, nullptr, y1, nullptr, nullptr, nullptr, flag);
        gemm_kernel<3, 4><<<dim3(32, 9, 4), 256, 0, stream>>>(
            y1, wTl + 2654208, FF_, b2, l * E_, h, nullptr, nullptr, nullptr, nullptr, flag);
    }
    out_kernel<<<4608, 256, 0, stream>>>(h, d_out, flag);
}

// Round 7
// 889.966 us; speedup vs baseline: 2.1311x; 1.0674x over previous
//
#include <hip/hip_runtime.h>

// ---------------------------------------------------------------------------
// AttentionStack: 6-layer transformer, B=2, SEQ=1024, E=576, H=16, DK=36.
// Inputs/outputs dtype auto-detected (f32 vs bf16) at runtime; internal
// pipeline: bf16 MFMA GEMMs (128x64 tiles, LDS-staged, split-K) + fp32
// residual stream. Attention: flash, kv-split across waves, XCD-swizzled.
// ---------------------------------------------------------------------------

#define E_    576
#define SEQ_  1024
#define B_    2
#define NH_   16
#define DK_   36
#define DKP_  64          // DK padded to 64 for MFMA K-steps of 32
#define NL_   6
#define FF_   2304
#define ROWS_ 2048        // B_*SEQ_

typedef unsigned short u16;
typedef unsigned int u32;
typedef float f32x4 __attribute__((ext_vector_type(4)));
typedef __bf16 bf16x8 __attribute__((ext_vector_type(8)));

#define MFMA16(a, b, c) __builtin_amdgcn_mfma_f32_16x16x32_bf16((a), (b), (c), 0, 0, 0)

__device__ __forceinline__ float bf2f(u16 u) {
    return __uint_as_float(((unsigned)u) << 16);
}
__device__ __forceinline__ u16 f2bf(float f) {
    unsigned u = __float_as_uint(f);
    u += 0x7fffu + ((u >> 16) & 1u);   // round-to-nearest-even
    return (u16)(u >> 16);
}
__device__ __forceinline__ float load_in(const void* p, size_t i, int isf32) {
    return isf32 ? ((const float*)p)[i] : bf2f(((const u16*)p)[i]);
}
__device__ __forceinline__ u16 load_in_bf(const void* p, size_t i, int isf32) {
    return isf32 ? f2bf(((const float*)p)[i]) : ((const u16*)p)[i];
}
__device__ __forceinline__ bf16x8 ldg8(const u16* p) {
    uint4 u = *(const uint4*)p;        // 16B aligned by construction
    bf16x8 r;
    __builtin_memcpy(&r, &u, 16);
    return r;
}
// async global->LDS, 16B per lane; LDS dest = wave-uniform base + lane*16
__device__ __forceinline__ void gload_lds16(const u16* g, u16* l) {
    __builtin_amdgcn_global_load_lds(
        (const __attribute__((address_space(1))) unsigned int*)g,
        (__attribute__((address_space(3))) unsigned int*)l, 16, 0, 0);
}

// ---------------------------------------------------------------------------
// Dtype detect: f32 data read as bf16 u16s shows huge magnitudes.
// ---------------------------------------------------------------------------
__global__ void detect_kernel(const u16* __restrict__ x, int* __restrict__ flag)
{
    __shared__ float red[4];
    int lane = threadIdx.x & 63, wave = threadIdx.x >> 6;
    float mx = 0.f;
    for (int i = threadIdx.x; i < 4096; i += 256) {
        float v = fabsf(bf2f(x[i]));
        if (v < 3e38f) mx = fmaxf(mx, v);
    }
    for (int off = 1; off < 64; off <<= 1) mx = fmaxf(mx, __shfl_xor(mx, off));
    if (lane == 0) red[wave] = mx;
    __syncthreads();
    if (threadIdx.x == 0) {
        float m = fmaxf(fmaxf(red[0], red[1]), fmaxf(red[2], red[3]));
        *flag = (m > 1e6f) ? 1 : 0;
    }
}

// ---------------------------------------------------------------------------
// Weight repack v2: W[K][N] -> W^T[N][K] bf16. 64x64 LDS tiles; coalesced
// f32 reads; u32-paired writes -> 128B contiguous per wave (no partial-line
// RMW; R6 showed WRITE_SIZE 2x ideal with 2B stores).
// grid (972, 1, 6), block 256.
// ---------------------------------------------------------------------------
__global__ __launch_bounds__(256) void repack_kernel(
    const void* __restrict__ wq, const void* __restrict__ wk,
    const void* __restrict__ wv, const void* __restrict__ wo,
    const void* __restrict__ w1, const void* __restrict__ w2,
    u16* __restrict__ wT, const int* __restrict__ flagp)
{
    __shared__ u16 tile[64][65];
    int isf32 = *flagp;
    int idx = blockIdx.x, l = blockIdx.z;
    const void* src;
    u16* dst;
    size_t sbase;
    int R, C, cx, ry;
    if (idx < 324) {                        // wq/wk/wv/wo: 576x576, 81 tiles ea
        int t4 = idx / 81, rem = idx - t4 * 81;
        ry = rem / 9; cx = rem % 9; R = 576; C = 576;
        src = (t4 == 0) ? wq : (t4 == 1) ? wk : (t4 == 2) ? wv : wo;
        sbase = (size_t)l * 331776;
        dst = wT + (size_t)l * 3981312 + t4 * 331776;
    } else if (idx < 648) {                 // w1: 576x2304 -> 2304x576
        int rem = idx - 324;
        ry = rem / 36; cx = rem % 36; R = 576; C = 2304;
        src = w1; sbase = (size_t)l * 1327104;
        dst = wT + (size_t)l * 3981312 + 1327104;
    } else {                                // w2: 2304x576 -> 576x2304
        int rem = idx - 648;
        ry = rem / 9; cx = rem % 9; R = 2304; C = 576;
        src = w2; sbase = (size_t)l * 1327104;
        dst = wT + (size_t)l * 3981312 + 2654208;
    }
    int r0 = ry * 64, c0 = cx * 64;
    int t = threadIdx.x;
    int cl = t & 63, rl = t >> 6;           // load: 64 cols x 4 rows per pass
    #pragma unroll
    for (int i = 0; i < 16; i++) {
        int rr = rl + i * 4;
        tile[rr][cl] = load_in_bf(src, sbase + (size_t)(r0 + rr) * C + c0 + cl, isf32);
    }
    __syncthreads();
    int p = t & 31, nl = t >> 5;            // store: 32 u32-pairs x 8 rows/pass
    #pragma unroll
    for (int i = 0; i < 8; i++) {
        int nn = nl + i * 8;
        u32 v = (u32)tile[2 * p][nn] | ((u32)tile[2 * p + 1][nn] << 16);
        u32* d32 = (u32*)(dst + (size_t)(c0 + nn) * R + r0);
        d32[p] = v;
    }
}

// ---------------------------------------------------------------------------
// Embed: h = rightshift(x, sos) + concat(pe0[t], pe1[h], pe2[w]); fp32 out.
// ---------------------------------------------------------------------------
__global__ void embed_kernel(
    const void* __restrict__ x, const void* __restrict__ sos,
    const void* __restrict__ pe0, const void* __restrict__ pe1,
    const void* __restrict__ pe2, float* __restrict__ h,
    const int* __restrict__ flagp)
{
    int isf32 = *flagp;
    int row = blockIdx.x;        // b*1024 + s
    int e = threadIdx.x;
    int s = row & 1023;
    float v = (s == 0) ? load_in(sos, e, isf32)
                       : load_in(x, (size_t)(row - 1) * E_ + e, isf32);
    int t = s >> 8, hh = (s >> 4) & 15, ww = s & 15;
    float p = (e < 192) ? load_in(pe0, t * 192 + e, isf32)
            : (e < 384) ? load_in(pe1, hh * 192 + e - 192, isf32)
                        : load_in(pe2, ww * 192 + e - 384, isf32);
    h[(size_t)row * E_ + e] = v + p;
}

// ---------------------------------------------------------------------------
// LayerNorm: y(bf16) = (h - mean)/sqrt(var+1e-5)*s + b. One wave per row.
// ---------------------------------------------------------------------------
__global__ __launch_bounds__(256) void ln_kernel(
    const float* __restrict__ h, u16* __restrict__ y,
    const void* __restrict__ sc, const void* __restrict__ bi,
    int off0, const int* __restrict__ flagp)
{
    int isf32 = *flagp;
    int lane = threadIdx.x & 63, wave = threadIdx.x >> 6;
    int row = blockIdx.x * 4 + wave;
    const float* hr = h + (size_t)row * E_;
    float v[9], s = 0.f, sq = 0.f;
    for (int j = 0; j < 9; j++) {
        v[j] = hr[lane + j * 64];
        s += v[j];
        sq += v[j] * v[j];
    }
    for (int off = 1; off < 64; off <<= 1) {
        s += __shfl_xor(s, off);
        sq += __shfl_xor(sq, off);
    }
    float mean = s * (1.0f / E_);
    float var = sq * (1.0f / E_) - mean * mean;
    float r = rsqrtf(var + 1e-5f);
    for (int j = 0; j < 9; j++) {
        int e = lane + j * 64;
        float sce = load_in(sc, off0 + e, isf32);
        float bie = load_in(bi, off0 + e, isf32);
        y[(size_t)row * E_ + e] = f2bf((v[j] - mean) * r * sce + bie);
    }
}

// ---------------------------------------------------------------------------
// GEMM v2: C[m,n] = sum_k A[m,k]*Bt[n,k]. Block tile 128(M)x64(N), 4 waves
// in 2x2 (wx=M-half, wy=N-half); each wave 4Mx2N 16x16 MFMA tiles.
// Per K-iter (BK=64): 6x global_load_lds(16B); per ks: 4 A + 2 B ds_read_b128
// feeding 8 MFMAs. XOR chunk swizzle keeps reads bank-spread.
// MODE 0: QKV (z picks wq/wk/wv; writes q(scaled)/k/vt padded to DKP)
// MODE 1: O-proj: h += A@woT + bo        (split-K 3, atomicAdd)
// MODE 2: MLP1:  y1 = gelu2(A@w1T + b1)  (N stride FF_)
// MODE 3: MLP2:  h += A@w2T + b2         (split-K 4, atomicAdd)
// ---------------------------------------------------------------------------
template <int MODE, int SPLITK>
__global__ __launch_bounds__(256) void gemm_kernel(
    const u16* __restrict__ A, const u16* __restrict__ BtBase, int K,
    const void* __restrict__ bias, int boff, float* __restrict__ hbuf,
    u16* __restrict__ out, u16* __restrict__ qb, u16* __restrict__ kb,
    u16* __restrict__ vtb, const int* __restrict__ flagp)
{
    __shared__ u16 lA[8192];     // 128 rows x 64 cols bf16 (16 KB)
    __shared__ u16 lB[4096];     //  64 rows x 64 cols bf16 ( 8 KB)
    int t = threadIdx.x;
    int lane = t & 63, wave = t >> 6;
    int lw = lane & 15, lq = lane >> 4;
    int wx = wave >> 1, wy = wave & 1;
    int m0 = blockIdx.x * 128, n0 = blockIdx.y * 64;
    int z = blockIdx.z / SPLITK, kz = blockIdx.z % SPLITK;
    int Ks = K / SPLITK, kbase = kz * Ks;

    const u16* Bt = BtBase + (MODE == 0 ? (size_t)z * 331776 : 0);
    // staging: thread t covers row t>>3 (+32/round), 16B chunk (t&7),
    // holding global chunk (t&7)^(row&7) (XOR swizzle).
    int rowS = t >> 3;
    int gc = (t & 7) ^ (rowS & 7);
    const u16* gA = A + (size_t)(m0 + rowS) * K + kbase + gc * 8;
    const u16* gB = Bt + (size_t)(n0 + rowS) * K + kbase + gc * 8;
    size_t rstep = (size_t)32 * K;

    f32x4 acc[4][2];
    for (int mi = 0; mi < 4; mi++)
        for (int ni = 0; ni < 2; ni++)
            for (int r = 0; r < 4; r++) acc[mi][ni][r] = 0.f;

    for (int kc = 0; kc < Ks; kc += 64) {
        #pragma unroll
        for (int ra = 0; ra < 4; ra++)
            gload_lds16(gA + ra * rstep + kc, &lA[ra * 2048 + t * 8]);
        #pragma unroll
        for (int rb = 0; rb < 2; rb++)
            gload_lds16(gB + rb * rstep + kc, &lB[rb * 2048 + t * 8]);
        __syncthreads();
        #pragma unroll
        for (int ks = 0; ks < 2; ks++) {
            int csw = ((ks * 4 + lq) ^ (lw & 7)) * 8;
            bf16x8 bf0 = ldg8(&lB[(wy * 32 + lw) * 64 + csw]);
            bf16x8 bf1 = ldg8(&lB[(wy * 32 + 16 + lw) * 64 + csw]);
            #pragma unroll
            for (int mi = 0; mi < 4; mi++) {
                bf16x8 af = ldg8(&lA[(wx * 64 + mi * 16 + lw) * 64 + csw]);
                acc[mi][0] = MFMA16(af, bf0, acc[mi][0]);
                acc[mi][1] = MFMA16(af, bf1, acc[mi][1]);
            }
        }
        __syncthreads();
    }

    int isf32 = (MODE != 0) ? *flagp : 0;
    #pragma unroll
    for (int ni = 0; ni < 2; ni++) {
        int n = n0 + wy * 32 + ni * 16 + lw;
        float bn = 0.f;
        if (MODE == 2 || ((MODE == 1 || MODE == 3) && kz == 0))
            bn = load_in(bias, boff + n, isf32);
        #pragma unroll
        for (int mi = 0; mi < 4; mi++) {
            #pragma unroll
            for (int r = 0; r < 4; r++) {
                int m = m0 + wx * 64 + mi * 16 + lq * 4 + r;
                float v = acc[mi][ni][r];
                if (MODE == 0) {
                    int b = m >> 10, s = m & 1023;
                    int head = n / 36, d = n - head * 36;
                    size_t bh = (size_t)(b * NH_ + head);
                    if (z == 0)
                        qb[(bh * SEQ_ + s) * DKP_ + d] = f2bf(v * (1.0f / 6.0f));
                    else if (z == 1)
                        kb[(bh * SEQ_ + s) * DKP_ + d] = f2bf(v);
                    else
                        vtb[(bh * DKP_ + d) * SEQ_ + s] = f2bf(v);
                } else if (MODE == 2) {
                    float tt = v + bn;
                    out[(size_t)m * FF_ + n] = f2bf(tt / (1.0f + __expf(-1.702f * tt)));
                } else {
                    atomicAdd(&hbuf[(size_t)m * E_ + n], v + bn);
                }
            }
        }
    }
}

// ---------------------------------------------------------------------------
// Flash attention v3: flat grid 2048, XCD-swizzled: bh = L&31 so all 64
// q-tile blocks of one (b,head) share L%8 -> same XCD L2 (K/V 256KB/bh).
// Block = 16 q-rows; 4 waves split the kv chunks (64 keys each) and merge
// partial (m,l,O) flash-decode style via LDS.
// dm decomposition: dm = sA[kvh] (uniform) * ew[r] (kv-invariant).
// ---------------------------------------------------------------------------
__global__ __launch_bounds__(256) void attn_kernel(
    const u16* __restrict__ qb, const u16* __restrict__ kb,
    const u16* __restrict__ vtb, u16* __restrict__ ob)
{
    __shared__ u32 plds[4][16][33];
    __shared__ float sm[4][16], sl[4][16];
    __shared__ float so[4][16][52];
    int lane = threadIdx.x & 63, wave = threadIdx.x >> 6;
    int lw = lane & 15, lq = lane >> 4;
    int L = blockIdx.x;
    int bh = L & 31;                      // XCD affinity: xcd ~ L%8 = bh%8
    int qt = 63 - (L >> 5);               // longest kv ranges launch first
    int head = bh & 15, b = bh >> 4;
    int q0 = qt * 16;

    const u16* qbase = qb + ((size_t)bh * SEQ_ + q0) * DKP_;
    bf16x8 qf0 = ldg8(qbase + lw * DKP_ + lq * 8);
    bf16x8 qf1 = ldg8(qbase + lw * DKP_ + 32 + lq * 8);

    int tq = q0 >> 8, hq = (q0 >> 4) & 15;
    float m_i[4], l_i[4], ew[4];
    f32x4 oacc[3];
    int qi[4];
    for (int r = 0; r < 4; r++) {
        m_i[r] = -1e30f;
        l_i[r] = 0.f;
        qi[r] = q0 + lq * 4 + r;
        ew[r] = __expf((float)abs(lw - (lq * 4 + r)) * (-1.0f / 33.0f));
    }
    for (int c = 0; c < 3; c++)
        for (int r = 0; r < 4; r++) oacc[c][r] = 0.f;

    int nch = (q0 + 79) >> 6;             // ceil((q0+16)/64)
    for (int c = wave; c < nch; c += 4) {
        int kv0 = c * 64;
        bool diag = (c == nch - 1);
        bf16x8 kf[4][2], vf[3][2];
        #pragma unroll
        for (int kvh = 0; kvh < 4; kvh++) {
            const u16* krow =
                kb + ((size_t)bh * SEQ_ + kv0 + kvh * 16 + lw) * DKP_ + lq * 8;
            kf[kvh][0] = ldg8(krow);
            kf[kvh][1] = ldg8(krow + 32);
        }
        #pragma unroll
        for (int c2 = 0; c2 < 3; c2++) {
            const u16* vrow =
                vtb + ((size_t)bh * DKP_ + c2 * 16 + lw) * SEQ_ + kv0 + lq * 8;
            vf[c2][0] = ldg8(vrow);
            vf[c2][1] = ldg8(vrow + 32);
        }
        f32x4 st[4];
        #pragma unroll
        for (int kvh = 0; kvh < 4; kvh++) {
            f32x4 tt;
            for (int r = 0; r < 4; r++) tt[r] = 0.f;
            tt = MFMA16(qf0, kf[kvh][0], tt);
            tt = MFMA16(qf1, kf[kvh][1], tt);
            st[kvh] = tt;
        }
        float sA[4];
        #pragma unroll
        for (int kvh = 0; kvh < 4; kvh++) {
            int kk = kv0 + kvh * 16;
            int d = abs((kk >> 8) - tq) + abs(((kk >> 4) & 15) - hq);
            sA[kvh] = __expf((float)d * (-1.0f / 33.0f));
        }
        #pragma unroll
        for (int r = 0; r < 4; r++) {
            float v0 = st[0][r] * (sA[0] * ew[r]);
            float v1 = st[1][r] * (sA[1] * ew[r]);
            float v2 = st[2][r] * (sA[2] * ew[r]);
            float v3 = st[3][r] * (sA[3] * ew[r]);
            if (diag) {
                if (kv0 + 0 * 16 + lw > qi[r]) v0 = -1e30f;
                if (kv0 + 1 * 16 + lw > qi[r]) v1 = -1e30f;
                if (kv0 + 2 * 16 + lw > qi[r]) v2 = -1e30f;
                if (kv0 + 3 * 16 + lw > qi[r]) v3 = -1e30f;
            }
            float m2 = fmaxf(fmaxf(v0, v1), fmaxf(v2, v3));
            for (int off = 1; off < 16; off <<= 1)
                m2 = fmaxf(m2, __shfl_xor(m2, off));
            float mn = fmaxf(m_i[r], m2);
            float alpha = __expf(m_i[r] - mn);
            m_i[r] = mn;
            float p0 = __expf(v0 - mn), p1 = __expf(v1 - mn);
            float p2 = __expf(v2 - mn), p3 = __expf(v3 - mn);
            u32 a01 = (u32)f2bf(p0) | ((u32)f2bf(p1) << 16);
            u32 a23 = (u32)f2bf(p2) | ((u32)f2bf(p3) << 16);
            u32 b01 = (u32)__shfl_xor((int)a01, 1);
            u32 b23 = (u32)__shfl_xor((int)a23, 1);
            if (!(lw & 1)) {
                int ro = lq * 4 + r, w2 = lw >> 1;
                plds[wave][ro][w2 + 0]  = ((b01 & 0xffffu) << 16) | (a01 & 0xffffu);
                plds[wave][ro][w2 + 8]  = (b01 & 0xffff0000u) | (a01 >> 16);
                plds[wave][ro][w2 + 16] = ((b23 & 0xffffu) << 16) | (a23 & 0xffffu);
                plds[wave][ro][w2 + 24] = (b23 & 0xffff0000u) | (a23 >> 16);
            }
            float rs = (p0 + p1) + (p2 + p3);
            for (int off = 1; off < 16; off <<= 1)
                rs += __shfl_xor(rs, off);
            l_i[r] = l_i[r] * alpha + rs;
            for (int c2 = 0; c2 < 3; c2++) oacc[c2][r] *= alpha;
        }
        __asm__ volatile("s_waitcnt lgkmcnt(0)" ::: "memory");
        uint4 u0 = *(const uint4*)&plds[wave][lw][lq * 4];
        uint4 u1 = *(const uint4*)&plds[wave][lw][16 + lq * 4];
        bf16x8 pf0, pf1;
        __builtin_memcpy(&pf0, &u0, 16);
        __builtin_memcpy(&pf1, &u1, 16);
        #pragma unroll
        for (int c2 = 0; c2 < 3; c2++) {
            oacc[c2] = MFMA16(pf0, vf[c2][0], oacc[c2]);
            oacc[c2] = MFMA16(pf1, vf[c2][1], oacc[c2]);
        }
    }
    #pragma unroll
    for (int r = 0; r < 4; r++) {
        int ro = lq * 4 + r;
        if (lw == 0) { sm[wave][ro] = m_i[r]; sl[wave][ro] = l_i[r]; }
        for (int c2 = 0; c2 < 3; c2++)
            so[wave][ro][c2 * 16 + lw] = oacc[c2][r];
    }
    __syncthreads();
    for (int i = threadIdx.x; i < 16 * DK_; i += 256) {
        int row = i / DK_, col = i - row * DK_;
        float M = fmaxf(fmaxf(sm[0][row], sm[1][row]),
                        fmaxf(sm[2][row], sm[3][row]));
        float Lm = 0.f, O = 0.f;
        #pragma unroll
        for (int w = 0; w < 4; w++) {
            float f = __expf(sm[w][row] - M);
            Lm += f * sl[w][row];
            O += f * so[w][row][col];
        }
        ob[((size_t)b * SEQ_ + q0 + row) * E_ + head * DK_ + col] = f2bf(O / Lm);
    }
}

// ---------------------------------------------------------------------------
__global__ void out_kernel(const float* __restrict__ h, void* __restrict__ out,
                           const int* __restrict__ flagp)
{
    int isf32 = *flagp;
    int i = blockIdx.x * blockDim.x + threadIdx.x;
    if (isf32) ((float*)out)[i] = h[i];
    else       ((u16*)out)[i] = f2bf(h[i]);
}

// ---------------------------------------------------------------------------
extern "C" void kernel_launch(void* const* d_in, const int* in_sizes, int n_in,
                              void* d_out, int out_size, void* d_ws,
                              size_t ws_size, hipStream_t stream)
{
    const void* x    = d_in[0];
    const void* sos  = d_in[1];
    const void* pe0  = d_in[2];
    const void* pe1  = d_in[3];
    const void* pe2  = d_in[4];
    const void* ln1s = d_in[5];
    const void* ln1b = d_in[6];
    const void* wq   = d_in[7];
    const void* wk   = d_in[8];
    const void* wv   = d_in[9];
    const void* wo   = d_in[10];
    const void* bo   = d_in[11];
    const void* ln2s = d_in[12];
    const void* ln2b = d_in[13];
    const void* w1   = d_in[14];
    const void* b1   = d_in[15];
    const void* w2   = d_in[16];
    const void* b2   = d_in[17];

    char* ws = (char*)d_ws;
    u16*   qbuf  = (u16*)(ws + 0);          //  4 MB  [B,H,SEQ,64] bf16
    u16*   kbuf  = (u16*)(ws + 4194304);    //  4 MB
    u16*   vtbuf = (u16*)(ws + 8388608);    //  4 MB  [B,H,64,SEQ] bf16
    float* h     = (float*)(ws + 12582912); //  4.7 MB fp32 residual stream
    u16*   y     = (u16*)(ws + 17301504);   //  2.36 MB LN output
    u16*   o     = (u16*)(ws + 19660800);   //  2.36 MB attention output
    u16*   y1    = (u16*)(ws + 22020096);   //  9.4 MB MLP hidden
    u16*   wT    = (u16*)(ws + 31457280);   // 47.8 MB repacked weights
    int*   flag  = (int*)(ws + 79233024);   // dtype flag

    // zero q/k/vt so DK->DKP padding lanes stay 0 (ws is 0xAA-poisoned)
    hipMemsetAsync(ws, 0, 12582912, stream);
    detect_kernel<<<1, 256, 0, stream>>>((const u16*)x, flag);
    repack_kernel<<<dim3(972, 1, 6), 256, 0, stream>>>(
        wq, wk, wv, wo, w1, w2, wT, flag);
    embed_kernel<<<ROWS_, E_, 0, stream>>>(x, sos, pe0, pe1, pe2, h, flag);

    for (int l = 0; l < NL_; l++) {
        u16* wTl = wT + (size_t)l * 3981312;
        ln_kernel<<<512, 256, 0, stream>>>(h, y, ln1s, ln1b, l * E_, flag);
        gemm_kernel<0, 1><<<dim3(16, 9, 3), 256, 0, stream>>>(
            y, wTl, E_, nullptr, 0, nullptr, nullptr, qbuf, kbuf, vtbuf, flag);
        attn_kernel<<<dim3(2048), 256, 0, stream>>>(qbuf, kbuf, vtbuf, o);
        gemm_kernel<1, 3><<<dim3(16, 9, 3), 256, 0, stream>>>(
            o, wTl + 995328, E_, bo, l * E_, h, nullptr, nullptr, nullptr, nullptr, flag);
        ln_kernel<<<512, 256, 0, stream>>>(h, y, ln2s, ln2b, l * E_, flag);
        gemm_kernel<2, 1><<<dim3(16, 36, 1), 256, 0, stream>>>(
            y, wTl + 1327104, E_, b1, l * FF_, nullptr, y1, nullptr, nullptr, nullptr, flag);
        gemm_kernel<3, 4><<<dim3(16, 9, 4), 256, 0, stream>>>(
            y1, wTl + 2654208, FF_, b2, l * E_, h, nullptr, nullptr, nullptr, nullptr, flag);
    }
    out_kernel<<<4608, 256, 0, stream>>>(h, d_out, flag);
}

// Round 8
// 868.679 us; speedup vs baseline: 2.1833x; 1.0245x over previous
//
#include <hip/hip_runtime.h>

// ---------------------------------------------------------------------------
// AttentionStack: 6-layer transformer, B=2, SEQ=1024, E=576, H=16, DK=36.
// Inputs/outputs dtype auto-detected (f32 vs bf16) at runtime; internal
// pipeline: bf16 MFMA GEMMs (128x64 tiles, LDS-staged, split-K) + fp32
// residual stream. Attention: flash, kv-split across waves, XCD-swizzled.
// ---------------------------------------------------------------------------

#define E_    576
#define SEQ_  1024
#define B_    2
#define NH_   16
#define DK_   36
#define DKP_  64          // DK padded to 64 for MFMA K-steps of 32
#define NL_   6
#define FF_   2304
#define ROWS_ 2048        // B_*SEQ_

typedef unsigned short u16;
typedef unsigned int u32;
typedef float f32x4 __attribute__((ext_vector_type(4)));
typedef __bf16 bf16x8 __attribute__((ext_vector_type(8)));

#define MFMA16(a, b, c) __builtin_amdgcn_mfma_f32_16x16x32_bf16((a), (b), (c), 0, 0, 0)

__device__ __forceinline__ float bf2f(u16 u) {
    return __uint_as_float(((unsigned)u) << 16);
}
__device__ __forceinline__ u16 f2bf(float f) {
    unsigned u = __float_as_uint(f);
    u += 0x7fffu + ((u >> 16) & 1u);   // round-to-nearest-even
    return (u16)(u >> 16);
}
__device__ __forceinline__ float load_in(const void* p, size_t i, int isf32) {
    return isf32 ? ((const float*)p)[i] : bf2f(((const u16*)p)[i]);
}
__device__ __forceinline__ u16 load_in_bf(const void* p, size_t i, int isf32) {
    return isf32 ? f2bf(((const float*)p)[i]) : ((const u16*)p)[i];
}
__device__ __forceinline__ bf16x8 ldg8(const u16* p) {
    uint4 u = *(const uint4*)p;        // 16B aligned by construction
    bf16x8 r;
    __builtin_memcpy(&r, &u, 16);
    return r;
}
// async global->LDS, 16B per lane; LDS dest = wave-uniform base + lane*16
__device__ __forceinline__ void gload_lds16(const u16* g, u16* l) {
    __builtin_amdgcn_global_load_lds(
        (const __attribute__((address_space(1))) unsigned int*)g,
        (__attribute__((address_space(3))) unsigned int*)l, 16, 0, 0);
}

// ---------------------------------------------------------------------------
// Dtype detect: f32 data read as bf16 u16s shows huge magnitudes.
// ---------------------------------------------------------------------------
__global__ void detect_kernel(const u16* __restrict__ x, int* __restrict__ flag)
{
    __shared__ float red[4];
    int lane = threadIdx.x & 63, wave = threadIdx.x >> 6;
    float mx = 0.f;
    for (int i = threadIdx.x; i < 4096; i += 256) {
        float v = fabsf(bf2f(x[i]));
        if (v < 3e38f) mx = fmaxf(mx, v);
    }
    for (int off = 1; off < 64; off <<= 1) mx = fmaxf(mx, __shfl_xor(mx, off));
    if (lane == 0) red[wave] = mx;
    __syncthreads();
    if (threadIdx.x == 0) {
        float m = fmaxf(fmaxf(red[0], red[1]), fmaxf(red[2], red[3]));
        *flag = (m > 1e6f) ? 1 : 0;
    }
}

// ---------------------------------------------------------------------------
// Weight repack v3: W[K][N] -> W^T[N][K] bf16. 64x64 tiles.
// Load phase: float4 (16B) vector loads (uint2 for bf16 input), pack to
// bf16-pair u32 words in registers, LDS stored as u32 [64][33] (pad 66 u16
// -> store-phase banks 2p%32, 2-way = free). R7 showed VGPR=12 serialized
// the scalar loads (2.9 TB/s eff); 4 independent 16B loads/thread fix ILP.
// Store phase: u32-pair writes, 128B contiguous per 32 lanes (proven v2).
// grid (972, 1, 6), block 256.
// ---------------------------------------------------------------------------
__global__ __launch_bounds__(256) void repack_kernel(
    const void* __restrict__ wq, const void* __restrict__ wk,
    const void* __restrict__ wv, const void* __restrict__ wo,
    const void* __restrict__ w1, const void* __restrict__ w2,
    u16* __restrict__ wT, const int* __restrict__ flagp)
{
    __shared__ u32 tile[64 * 33];           // [row][col-pair], pad 33 words
    int isf32 = *flagp;
    int idx = blockIdx.x, l = blockIdx.z;
    const void* src;
    u16* dst;
    size_t sbase;
    int R, C, cx, ry;
    if (idx < 324) {                        // wq/wk/wv/wo: 576x576, 81 tiles ea
        int t4 = idx / 81, rem = idx - t4 * 81;
        ry = rem / 9; cx = rem % 9; R = 576; C = 576;
        src = (t4 == 0) ? wq : (t4 == 1) ? wk : (t4 == 2) ? wv : wo;
        sbase = (size_t)l * 331776;
        dst = wT + (size_t)l * 3981312 + t4 * 331776;
    } else if (idx < 648) {                 // w1: 576x2304 -> 2304x576
        int rem = idx - 324;
        ry = rem / 36; cx = rem % 36; R = 576; C = 2304;
        src = w1; sbase = (size_t)l * 1327104;
        dst = wT + (size_t)l * 3981312 + 1327104;
    } else {                                // w2: 2304x576 -> 576x2304
        int rem = idx - 648;
        ry = rem / 9; cx = rem % 9; R = 2304; C = 576;
        src = w2; sbase = (size_t)l * 1327104;
        dst = wT + (size_t)l * 3981312 + 2654208;
    }
    int r0 = ry * 64, c0 = cx * 64;
    int t = threadIdx.x;
    // load: thread t covers row (t>>4)+16i, 4-float chunk t&15
    int chunk = t & 15, row = t >> 4;
    #pragma unroll
    for (int i = 0; i < 4; i++) {
        int rr = row + i * 16;
        size_t g = sbase + (size_t)(r0 + rr) * C + c0 + chunk * 4;
        u32 lo, hi;
        if (isf32) {
            f32x4 v = *(const f32x4*)((const float*)src + g);
            lo = (u32)f2bf(v[0]) | ((u32)f2bf(v[1]) << 16);
            hi = (u32)f2bf(v[2]) | ((u32)f2bf(v[3]) << 16);
        } else {
            uint2 v = *(const uint2*)((const u16*)src + g);
            lo = v.x; hi = v.y;
        }
        tile[rr * 33 + chunk * 2] = lo;
        tile[rr * 33 + chunk * 2 + 1] = hi;
    }
    __syncthreads();
    // store: thread t covers k-pair p=t&31 of output row nn=(t>>5)+8i
    int p = t & 31, nl = t >> 5;
    #pragma unroll
    for (int i = 0; i < 8; i++) {
        int nn = nl + i * 8;
        u32 wA = tile[(2 * p) * 33 + (nn >> 1)];
        u32 wB = tile[(2 * p + 1) * 33 + (nn >> 1)];
        u32 a = (nn & 1) ? (wA >> 16) : (wA & 0xffffu);
        u32 b = (nn & 1) ? (wB >> 16) : (wB & 0xffffu);
        u32* d32 = (u32*)(dst + (size_t)(c0 + nn) * R + r0);
        d32[p] = a | (b << 16);
    }
}

// ---------------------------------------------------------------------------
// Embed: h = rightshift(x, sos) + concat(pe0[t], pe1[h], pe2[w]); fp32 out.
// ---------------------------------------------------------------------------
__global__ void embed_kernel(
    const void* __restrict__ x, const void* __restrict__ sos,
    const void* __restrict__ pe0, const void* __restrict__ pe1,
    const void* __restrict__ pe2, float* __restrict__ h,
    const int* __restrict__ flagp)
{
    int isf32 = *flagp;
    int row = blockIdx.x;        // b*1024 + s
    int e = threadIdx.x;
    int s = row & 1023;
    float v = (s == 0) ? load_in(sos, e, isf32)
                       : load_in(x, (size_t)(row - 1) * E_ + e, isf32);
    int t = s >> 8, hh = (s >> 4) & 15, ww = s & 15;
    float p = (e < 192) ? load_in(pe0, t * 192 + e, isf32)
            : (e < 384) ? load_in(pe1, hh * 192 + e - 192, isf32)
                        : load_in(pe2, ww * 192 + e - 384, isf32);
    h[(size_t)row * E_ + e] = v + p;
}

// ---------------------------------------------------------------------------
// LayerNorm: y(bf16) = (h - mean)/sqrt(var+1e-5)*s + b. One wave per row.
// ---------------------------------------------------------------------------
__global__ __launch_bounds__(256) void ln_kernel(
    const float* __restrict__ h, u16* __restrict__ y,
    const void* __restrict__ sc, const void* __restrict__ bi,
    int off0, const int* __restrict__ flagp)
{
    int isf32 = *flagp;
    int lane = threadIdx.x & 63, wave = threadIdx.x >> 6;
    int row = blockIdx.x * 4 + wave;
    const float* hr = h + (size_t)row * E_;
    float v[9], s = 0.f, sq = 0.f;
    for (int j = 0; j < 9; j++) {
        v[j] = hr[lane + j * 64];
        s += v[j];
        sq += v[j] * v[j];
    }
    for (int off = 1; off < 64; off <<= 1) {
        s += __shfl_xor(s, off);
        sq += __shfl_xor(sq, off);
    }
    float mean = s * (1.0f / E_);
    float var = sq * (1.0f / E_) - mean * mean;
    float r = rsqrtf(var + 1e-5f);
    for (int j = 0; j < 9; j++) {
        int e = lane + j * 64;
        float sce = load_in(sc, off0 + e, isf32);
        float bie = load_in(bi, off0 + e, isf32);
        y[(size_t)row * E_ + e] = f2bf((v[j] - mean) * r * sce + bie);
    }
}

// ---------------------------------------------------------------------------
// GEMM v2: C[m,n] = sum_k A[m,k]*Bt[n,k]. Block tile 128(M)x64(N), 4 waves
// in 2x2 (wx=M-half, wy=N-half); each wave 4Mx2N 16x16 MFMA tiles.
// Per K-iter (BK=64): 6x global_load_lds(16B); per ks: 4 A + 2 B ds_read_b128
// feeding 8 MFMAs. XOR chunk swizzle keeps reads bank-spread.
// MODE 0: QKV (z picks wq/wk/wv; writes q(scaled)/k/vt padded to DKP)
// MODE 1: O-proj: h += A@woT + bo        (split-K 3, atomicAdd)
// MODE 2: MLP1:  y1 = gelu2(A@w1T + b1)  (N stride FF_)
// MODE 3: MLP2:  h += A@w2T + b2         (split-K 4, atomicAdd)
// ---------------------------------------------------------------------------
template <int MODE, int SPLITK>
__global__ __launch_bounds__(256) void gemm_kernel(
    const u16* __restrict__ A, const u16* __restrict__ BtBase, int K,
    const void* __restrict__ bias, int boff, float* __restrict__ hbuf,
    u16* __restrict__ out, u16* __restrict__ qb, u16* __restrict__ kb,
    u16* __restrict__ vtb, const int* __restrict__ flagp)
{
    __shared__ u16 lA[8192];     // 128 rows x 64 cols bf16 (16 KB)
    __shared__ u16 lB[4096];     //  64 rows x 64 cols bf16 ( 8 KB)
    int t = threadIdx.x;
    int lane = t & 63, wave = t >> 6;
    int lw = lane & 15, lq = lane >> 4;
    int wx = wave >> 1, wy = wave & 1;
    int m0 = blockIdx.x * 128, n0 = blockIdx.y * 64;
    int z = blockIdx.z / SPLITK, kz = blockIdx.z % SPLITK;
    int Ks = K / SPLITK, kbase = kz * Ks;

    const u16* Bt = BtBase + (MODE == 0 ? (size_t)z * 331776 : 0);
    int rowS = t >> 3;
    int gc = (t & 7) ^ (rowS & 7);
    const u16* gA = A + (size_t)(m0 + rowS) * K + kbase + gc * 8;
    const u16* gB = Bt + (size_t)(n0 + rowS) * K + kbase + gc * 8;
    size_t rstep = (size_t)32 * K;

    f32x4 acc[4][2];
    for (int mi = 0; mi < 4; mi++)
        for (int ni = 0; ni < 2; ni++)
            for (int r = 0; r < 4; r++) acc[mi][ni][r] = 0.f;

    for (int kc = 0; kc < Ks; kc += 64) {
        #pragma unroll
        for (int ra = 0; ra < 4; ra++)
            gload_lds16(gA + ra * rstep + kc, &lA[ra * 2048 + t * 8]);
        #pragma unroll
        for (int rb = 0; rb < 2; rb++)
            gload_lds16(gB + rb * rstep + kc, &lB[rb * 2048 + t * 8]);
        __syncthreads();
        #pragma unroll
        for (int ks = 0; ks < 2; ks++) {
            int csw = ((ks * 4 + lq) ^ (lw & 7)) * 8;
            bf16x8 bf0 = ldg8(&lB[(wy * 32 + lw) * 64 + csw]);
            bf16x8 bf1 = ldg8(&lB[(wy * 32 + 16 + lw) * 64 + csw]);
            #pragma unroll
            for (int mi = 0; mi < 4; mi++) {
                bf16x8 af = ldg8(&lA[(wx * 64 + mi * 16 + lw) * 64 + csw]);
                acc[mi][0] = MFMA16(af, bf0, acc[mi][0]);
                acc[mi][1] = MFMA16(af, bf1, acc[mi][1]);
            }
        }
        __syncthreads();
    }

    int isf32 = (MODE != 0) ? *flagp : 0;
    #pragma unroll
    for (int ni = 0; ni < 2; ni++) {
        int n = n0 + wy * 32 + ni * 16 + lw;
        float bn = 0.f;
        if (MODE == 2 || ((MODE == 1 || MODE == 3) && kz == 0))
            bn = load_in(bias, boff + n, isf32);
        #pragma unroll
        for (int mi = 0; mi < 4; mi++) {
            #pragma unroll
            for (int r = 0; r < 4; r++) {
                int m = m0 + wx * 64 + mi * 16 + lq * 4 + r;
                float v = acc[mi][ni][r];
                if (MODE == 0) {
                    int b = m >> 10, s = m & 1023;
                    int head = n / 36, d = n - head * 36;
                    size_t bh = (size_t)(b * NH_ + head);
                    if (z == 0)
                        qb[(bh * SEQ_ + s) * DKP_ + d] = f2bf(v * (1.0f / 6.0f));
                    else if (z == 1)
                        kb[(bh * SEQ_ + s) * DKP_ + d] = f2bf(v);
                    else
                        vtb[(bh * DKP_ + d) * SEQ_ + s] = f2bf(v);
                } else if (MODE == 2) {
                    float tt = v + bn;
                    out[(size_t)m * FF_ + n] = f2bf(tt / (1.0f + __expf(-1.702f * tt)));
                } else {
                    atomicAdd(&hbuf[(size_t)m * E_ + n], v + bn);
                }
            }
        }
    }
}

// ---------------------------------------------------------------------------
// Flash attention v3: flat grid 2048, XCD-swizzled: bh = L&31 so all 64
// q-tile blocks of one (b,head) share L%8 -> same XCD L2 (K/V 256KB/bh).
// Block = 16 q-rows; 4 waves split the kv chunks (64 keys each) and merge
// partial (m,l,O) flash-decode style via LDS.
// dm decomposition: dm = sA[kvh] (uniform) * ew[r] (kv-invariant).
// ---------------------------------------------------------------------------
__global__ __launch_bounds__(256) void attn_kernel(
    const u16* __restrict__ qb, const u16* __restrict__ kb,
    const u16* __restrict__ vtb, u16* __restrict__ ob)
{
    __shared__ u32 plds[4][16][33];
    __shared__ float sm[4][16], sl[4][16];
    __shared__ float so[4][16][52];
    int lane = threadIdx.x & 63, wave = threadIdx.x >> 6;
    int lw = lane & 15, lq = lane >> 4;
    int L = blockIdx.x;
    int bh = L & 31;                      // XCD affinity: xcd ~ L%8 = bh%8
    int qt = 63 - (L >> 5);               // longest kv ranges launch first
    int head = bh & 15, b = bh >> 4;
    int q0 = qt * 16;

    const u16* qbase = qb + ((size_t)bh * SEQ_ + q0) * DKP_;
    bf16x8 qf0 = ldg8(qbase + lw * DKP_ + lq * 8);
    bf16x8 qf1 = ldg8(qbase + lw * DKP_ + 32 + lq * 8);

    int tq = q0 >> 8, hq = (q0 >> 4) & 15;
    float m_i[4], l_i[4], ew[4];
    f32x4 oacc[3];
    int qi[4];
    for (int r = 0; r < 4; r++) {
        m_i[r] = -1e30f;
        l_i[r] = 0.f;
        qi[r] = q0 + lq * 4 + r;
        ew[r] = __expf((float)abs(lw - (lq * 4 + r)) * (-1.0f / 33.0f));
    }
    for (int c = 0; c < 3; c++)
        for (int r = 0; r < 4; r++) oacc[c][r] = 0.f;

    int nch = (q0 + 79) >> 6;             // ceil((q0+16)/64)
    for (int c = wave; c < nch; c += 4) {
        int kv0 = c * 64;
        bool diag = (c == nch - 1);
        bf16x8 kf[4][2], vf[3][2];
        #pragma unroll
        for (int kvh = 0; kvh < 4; kvh++) {
            const u16* krow =
                kb + ((size_t)bh * SEQ_ + kv0 + kvh * 16 + lw) * DKP_ + lq * 8;
            kf[kvh][0] = ldg8(krow);
            kf[kvh][1] = ldg8(krow + 32);
        }
        #pragma unroll
        for (int c2 = 0; c2 < 3; c2++) {
            const u16* vrow =
                vtb + ((size_t)bh * DKP_ + c2 * 16 + lw) * SEQ_ + kv0 + lq * 8;
            vf[c2][0] = ldg8(vrow);
            vf[c2][1] = ldg8(vrow + 32);
        }
        f32x4 st[4];
        #pragma unroll
        for (int kvh = 0; kvh < 4; kvh++) {
            f32x4 tt;
            for (int r = 0; r < 4; r++) tt[r] = 0.f;
            tt = MFMA16(qf0, kf[kvh][0], tt);
            tt = MFMA16(qf1, kf[kvh][1], tt);
            st[kvh] = tt;
        }
        float sA[4];
        #pragma unroll
        for (int kvh = 0; kvh < 4; kvh++) {
            int kk = kv0 + kvh * 16;
            int d = abs((kk >> 8) - tq) + abs(((kk >> 4) & 15) - hq);
            sA[kvh] = __expf((float)d * (-1.0f / 33.0f));
        }
        #pragma unroll
        for (int r = 0; r < 4; r++) {
            float v0 = st[0][r] * (sA[0] * ew[r]);
            float v1 = st[1][r] * (sA[1] * ew[r]);
            float v2 = st[2][r] * (sA[2] * ew[r]);
            float v3 = st[3][r] * (sA[3] * ew[r]);
            if (diag) {
                if (kv0 + 0 * 16 + lw > qi[r]) v0 = -1e30f;
                if (kv0 + 1 * 16 + lw > qi[r]) v1 = -1e30f;
                if (kv0 + 2 * 16 + lw > qi[r]) v2 = -1e30f;
                if (kv0 + 3 * 16 + lw > qi[r]) v3 = -1e30f;
            }
            float m2 = fmaxf(fmaxf(v0, v1), fmaxf(v2, v3));
            for (int off = 1; off < 16; off <<= 1)
                m2 = fmaxf(m2, __shfl_xor(m2, off));
            float mn = fmaxf(m_i[r], m2);
            float alpha = __expf(m_i[r] - mn);
            m_i[r] = mn;
            float p0 = __expf(v0 - mn), p1 = __expf(v1 - mn);
            float p2 = __expf(v2 - mn), p3 = __expf(v3 - mn);
            u32 a01 = (u32)f2bf(p0) | ((u32)f2bf(p1) << 16);
            u32 a23 = (u32)f2bf(p2) | ((u32)f2bf(p3) << 16);
            u32 b01 = (u32)__shfl_xor((int)a01, 1);
            u32 b23 = (u32)__shfl_xor((int)a23, 1);
            if (!(lw & 1)) {
                int ro = lq * 4 + r, w2 = lw >> 1;
                plds[wave][ro][w2 + 0]  = ((b01 & 0xffffu) << 16) | (a01 & 0xffffu);
                plds[wave][ro][w2 + 8]  = (b01 & 0xffff0000u) | (a01 >> 16);
                plds[wave][ro][w2 + 16] = ((b23 & 0xffffu) << 16) | (a23 & 0xffffu);
                plds[wave][ro][w2 + 24] = (b23 & 0xffff0000u) | (a23 >> 16);
            }
            float rs = (p0 + p1) + (p2 + p3);
            for (int off = 1; off < 16; off <<= 1)
                rs += __shfl_xor(rs, off);
            l_i[r] = l_i[r] * alpha + rs;
            for (int c2 = 0; c2 < 3; c2++) oacc[c2][r] *= alpha;
        }
        __asm__ volatile("s_waitcnt lgkmcnt(0)" ::: "memory");
        uint4 u0 = *(const uint4*)&plds[wave][lw][lq * 4];
        uint4 u1 = *(const uint4*)&plds[wave][lw][16 + lq * 4];
        bf16x8 pf0, pf1;
        __builtin_memcpy(&pf0, &u0, 16);
        __builtin_memcpy(&pf1, &u1, 16);
        #pragma unroll
        for (int c2 = 0; c2 < 3; c2++) {
            oacc[c2] = MFMA16(pf0, vf[c2][0], oacc[c2]);
            oacc[c2] = MFMA16(pf1, vf[c2][1], oacc[c2]);
        }
    }
    #pragma unroll
    for (int r = 0; r < 4; r++) {
        int ro = lq * 4 + r;
        if (lw == 0) { sm[wave][ro] = m_i[r]; sl[wave][ro] = l_i[r]; }
        for (int c2 = 0; c2 < 3; c2++)
            so[wave][ro][c2 * 16 + lw] = oacc[c2][r];
    }
    __syncthreads();
    for (int i = threadIdx.x; i < 16 * DK_; i += 256) {
        int row = i / DK_, col = i - row * DK_;
        float M = fmaxf(fmaxf(sm[0][row], sm[1][row]),
                        fmaxf(sm[2][row], sm[3][row]));
        float Lm = 0.f, O = 0.f;
        #pragma unroll
        for (int w = 0; w < 4; w++) {
            float f = __expf(sm[w][row] - M);
            Lm += f * sl[w][row];
            O += f * so[w][row][col];
        }
        ob[((size_t)b * SEQ_ + q0 + row) * E_ + head * DK_ + col] = f2bf(O / Lm);
    }
}

// ---------------------------------------------------------------------------
__global__ void out_kernel(const float* __restrict__ h, void* __restrict__ out,
                           const int* __restrict__ flagp)
{
    int isf32 = *flagp;
    int i = blockIdx.x * blockDim.x + threadIdx.x;
    if (isf32) ((float*)out)[i] = h[i];
    else       ((u16*)out)[i] = f2bf(h[i]);
}

// ---------------------------------------------------------------------------
extern "C" void kernel_launch(void* const* d_in, const int* in_sizes, int n_in,
                              void* d_out, int out_size, void* d_ws,
                              size_t ws_size, hipStream_t stream)
{
    const void* x    = d_in[0];
    const void* sos  = d_in[1];
    const void* pe0  = d_in[2];
    const void* pe1  = d_in[3];
    const void* pe2  = d_in[4];
    const void* ln1s = d_in[5];
    const void* ln1b = d_in[6];
    const void* wq   = d_in[7];
    const void* wk   = d_in[8];
    const void* wv   = d_in[9];
    const void* wo   = d_in[10];
    const void* bo   = d_in[11];
    const void* ln2s = d_in[12];
    const void* ln2b = d_in[13];
    const void* w1   = d_in[14];
    const void* b1   = d_in[15];
    const void* w2   = d_in[16];
    const void* b2   = d_in[17];

    char* ws = (char*)d_ws;
    u16*   qbuf  = (u16*)(ws + 0);          //  4 MB  [B,H,SEQ,64] bf16
    u16*   kbuf  = (u16*)(ws + 4194304);    //  4 MB
    u16*   vtbuf = (u16*)(ws + 8388608);    //  4 MB  [B,H,64,SEQ] bf16
    float* h     = (float*)(ws + 12582912); //  4.7 MB fp32 residual stream
    u16*   y     = (u16*)(ws + 17301504);   //  2.36 MB LN output
    u16*   o     = (u16*)(ws + 19660800);   //  2.36 MB attention output
    u16*   y1    = (u16*)(ws + 22020096);   //  9.4 MB MLP hidden
    u16*   wT    = (u16*)(ws + 31457280);   // 47.8 MB repacked weights
    int*   flag  = (int*)(ws + 79233024);   // dtype flag

    // zero q/k/vt so DK->DKP padding lanes stay 0 (ws is 0xAA-poisoned)
    hipMemsetAsync(ws, 0, 12582912, stream);
    detect_kernel<<<1, 256, 0, stream>>>((const u16*)x, flag);
    repack_kernel<<<dim3(972, 1, 6), 256, 0, stream>>>(
        wq, wk, wv, wo, w1, w2, wT, flag);
    embed_kernel<<<ROWS_, E_, 0, stream>>>(x, sos, pe0, pe1, pe2, h, flag);

    for (int l = 0; l < NL_; l++) {
        u16* wTl = wT + (size_t)l * 3981312;
        ln_kernel<<<512, 256, 0, stream>>>(h, y, ln1s, ln1b, l * E_, flag);
        gemm_kernel<0, 1><<<dim3(16, 9, 3), 256, 0, stream>>>(
            y, wTl, E_, nullptr, 0, nullptr, nullptr, qbuf, kbuf, vtbuf, flag);
        attn_kernel<<<dim3(2048), 256, 0, stream>>>(qbuf, kbuf, vtbuf, o);
        gemm_kernel<1, 3><<<dim3(16, 9, 3), 256, 0, stream>>>(
            o, wTl + 995328, E_, bo, l * E_, h, nullptr, nullptr, nullptr, nullptr, flag);
        ln_kernel<<<512, 256, 0, stream>>>(h, y, ln2s, ln2b, l * E_, flag);
        gemm_kernel<2, 1><<<dim3(16, 36, 1), 256, 0, stream>>>(
            y, wTl + 1327104, E_, b1, l * FF_, nullptr, y1, nullptr, nullptr, nullptr, flag);
        gemm_kernel<3, 4><<<dim3(16, 9, 4), 256, 0, stream>>>(
            y1, wTl + 2654208, FF_, b2, l * E_, h, nullptr, nullptr, nullptr, nullptr, flag);
    }
    out_kernel<<<4608, 256, 0, stream>>>(h, d_out, flag);
}